// Round 14
// baseline (682.951 us; speedup 1.0000x reference)
//
#include <hip/hip_runtime.h>

#define HID 128
#define LDP 136   // padded LDS row stride in bf16 elems (272 B)

typedef short s16x8 __attribute__((ext_vector_type(8)));
typedef float f32x4 __attribute__((ext_vector_type(4)));

__device__ __forceinline__ float bf2f(unsigned int u) {
  union { unsigned int i; float f; } v; v.i = u << 16; return v.f;
}
__device__ __forceinline__ float asf(unsigned int u) {
  union { unsigned int i; float f; } v; v.i = u; return v.f;
}
__device__ __forceinline__ unsigned short f2bf(float f) {
  union { float f; unsigned int i; } v; v.f = f;
  unsigned int r = v.i + 0x7fffu + ((v.i >> 16) & 1u);
  return (unsigned short)(r >> 16);
}

// ---------------- zero fill (vectorized) ----------------
__global__ void k_zero4(float4* __restrict__ p, size_t n4) {
  size_t i = (size_t)blockIdx.x * blockDim.x + threadIdx.x;
  if (i < n4) p[i] = (float4){0.f, 0.f, 0.f, 0.f};
}

// ---------------- counting sort ----------------
__global__ void k_hist(const int* __restrict__ dst, int* __restrict__ deg, int nE) {
  int e = blockIdx.x * blockDim.x + threadIdx.x;
  if (e < nE) atomicAdd(&deg[dst[e]], 1);
}

__global__ void k_scanA(const int* __restrict__ deg, int* __restrict__ bsum) {
  __shared__ int ss[256];
  int t = threadIdx.x;
  ss[t] = deg[blockIdx.x * 256 + t];
  __syncthreads();
  for (int off = 128; off; off >>= 1) {
    if (t < off) ss[t] += ss[t + off];
    __syncthreads();
  }
  if (t == 0) bsum[blockIdx.x] = ss[0];
}

__global__ void k_scanB(const int* __restrict__ bsum, int* __restrict__ bsumx, int NB) {
  __shared__ int sd[512];
  int t = threadIdx.x;
  int v = (t < NB) ? bsum[t] : 0;
  sd[t] = v;
  __syncthreads();
  for (int off = 1; off < 512; off <<= 1) {
    int a = (t >= off) ? sd[t - off] : 0;
    __syncthreads();
    sd[t] += a;
    __syncthreads();
  }
  if (t < NB) bsumx[t] = sd[t] - v;
}

// exclusive scan to BOTH cursor (mutated by scatter) and rowptr (kept)
__global__ void k_scanC(const int* __restrict__ deg, const int* __restrict__ bsumx,
                        int* __restrict__ cursor, int* __restrict__ rowptr) {
  __shared__ int ss[256];
  int t = threadIdx.x, i = blockIdx.x * 256 + t;
  int v = deg[i];
  ss[t] = v;
  __syncthreads();
  for (int off = 1; off < 256; off <<= 1) {
    int a = (t >= off) ? ss[t - off] : 0;
    __syncthreads();
    ss[t] += a;
    __syncthreads();
  }
  int ex = ss[t] - v + bsumx[blockIdx.x];
  cursor[i] = ex;
  rowptr[i] = ex;
}

// permute: only src and the edge id (8 B random writes)
__global__ void k_scatter(const int* __restrict__ src, const int* __restrict__ dst,
                          int* __restrict__ cursor,
                          int* __restrict__ src_s, int* __restrict__ esort, int nE) {
  int e = blockIdx.x * blockDim.x + threadIdx.x;
  if (e >= nE) return;
  int d = dst[e];
  int pos = atomicAdd(&cursor[d], 1);
  src_s[pos] = src[e];
  esort[pos] = e;
}

// ---------------- transpose weights to bf16 ----------------
__global__ void k_prep_w(const float* __restrict__ ew2, const float* __restrict__ cw1,
                         const float* __restrict__ cw2, unsigned short* __restrict__ wT) {
  int idx = blockIdx.x * blockDim.x + threadIdx.x;
  if (idx >= 7 * 16384) return;
  int m = idx >> 14, i = idx & 16383;
  int n = i >> 7, k = i & 127;
  const float* s = (m == 0) ? ew2 : (m <= 3 ? cw1 + (size_t)(m - 1) * 16384
                                            : cw2 + (size_t)(m - 4) * 16384);
  wT[idx] = f2bf(s[k * 128 + n]);
}

// ---------------- node encoder ----------------
__global__ void k_node_enc(const float* __restrict__ x, const float* __restrict__ w,
                           const float* __restrict__ b, unsigned short* __restrict__ h16, int nN) {
  int idx = blockIdx.x * blockDim.x + threadIdx.x;
  if (idx >= nN * HID) return;
  int i = idx >> 7, j = idx & 127;
  float acc = b[j];
  const float* xr = x + (size_t)i * 7;
#pragma unroll
  for (int k = 0; k < 7; ++k) acc += xr[k] * w[k * HID + j];
  h16[idx] = f2bf(acc);
}

// ---------------- one-time edge encoder GEMM -> echunk (chunk-major bf16) ----------------
// echunk halfword layout: [chunk=edge/8][col 0..127][j=edge%8]
__global__ void __launch_bounds__(256) k_edge_gemm(
    const float* __restrict__ ea, const int* __restrict__ esort,
    const float* __restrict__ ew1, const float* __restrict__ eb1,
    const unsigned short* __restrict__ w2t, const float* __restrict__ eb2,
    unsigned short* __restrict__ echunk, int nE) {
  __shared__ __attribute__((aligned(16))) unsigned short ts1[128 * LDP];
  __shared__ float eaL[384];
  __shared__ int esL[128];
  int tid = threadIdx.x;
  int e0 = blockIdx.x * 128;                      // nE % 128 == 0
  if (tid < 128) esL[tid] = esort[e0 + tid];
  __syncthreads();
  for (int i = tid; i < 384; i += 256) {
    int r = i / 3, c = i - r * 3;
    eaL[i] = ea[(size_t)esL[r] * 3 + c];
  }
  __syncthreads();
  {
    int j = tid & 127, r0 = (tid >> 7) * 64;
    float wa = ew1[j], wb = ew1[HID + j], wc = ew1[2 * HID + j], bj = eb1[j];
    for (int r = r0; r < r0 + 64; ++r) {
      float a = bj + eaL[r * 3] * wa + eaL[r * 3 + 1] * wb + eaL[r * 3 + 2] * wc;
      ts1[r * LDP + j] = f2bf(fmaxf(a, 0.f));
    }
  }
  __syncthreads();
  int wave = tid >> 6, lane = tid & 63;
  int l15 = lane & 15, quad = lane >> 4;
  int rbase = (wave >> 1) * 64, nbase = (wave & 1) * 64;
  f32x4 acc[4][4];
#pragma unroll
  for (int i = 0; i < 4; ++i)
#pragma unroll
    for (int j = 0; j < 4; ++j) acc[i][j] = (f32x4){0.f, 0.f, 0.f, 0.f};
  for (int kc = 0; kc < 4; ++kc) {
    int k0 = kc * 32 + quad * 8;
    s16x8 af[4], bf[4];
#pragma unroll
    for (int t = 0; t < 4; ++t)
      af[t] = *(const s16x8*)&ts1[(rbase + t * 16 + l15) * LDP + k0];
#pragma unroll
    for (int t = 0; t < 4; ++t)
      bf[t] = *(const s16x8*)&w2t[(size_t)(nbase + t * 16 + l15) * HID + k0];
#pragma unroll
    for (int i = 0; i < 4; ++i)
#pragma unroll
      for (int j = 0; j < 4; ++j)
        acc[i][j] = __builtin_amdgcn_mfma_f32_16x16x32_bf16(af[i], bf[j], acc[i][j], 0, 0, 0);
  }
  __syncthreads();   // all A-frag reads done before overwrite
  // e = acc + eb2 -> ts1 (row-major bf16; C/D layout: col=lane&15, row=quad*4+reg)
  {
    float ebv[4];
#pragma unroll
    for (int t = 0; t < 4; ++t) ebv[t] = eb2[nbase + t * 16 + l15];
#pragma unroll
    for (int tr = 0; tr < 4; ++tr)
#pragma unroll
      for (int reg = 0; reg < 4; ++reg) {
        int row = rbase + tr * 16 + quad * 4 + reg;
#pragma unroll
        for (int tc = 0; tc < 4; ++tc) {
          int col = nbase + tc * 16 + l15;
          ts1[row * LDP + col] = f2bf(acc[tr][tc][reg] + ebv[tc]);
        }
      }
  }
  __syncthreads();
  // chunk-major coalesced store: task = (chunk 0..15, colpair 0..63)
#pragma unroll
  for (int t = 0; t < 4; ++t) {
    int idx = t * 256 + tid;
    int ch = idx >> 6, cp = idx & 63;
    unsigned int r[8];
#pragma unroll
    for (int j = 0; j < 8; ++j)
      r[j] = *(const unsigned int*)&ts1[(ch * 8 + j) * LDP + cp * 2];
    uint4 lo, hi;
    unsigned int* lw = (unsigned int*)&lo;
    unsigned int* hw = (unsigned int*)&hi;
#pragma unroll
    for (int w = 0; w < 4; ++w) {
      lw[w] = (r[2 * w] & 0xffffu) | (r[2 * w + 1] << 16);
      hw[w] = (r[2 * w] >> 16) | (r[2 * w + 1] & 0xffff0000u);
    }
    size_t baseo = ((size_t)(e0 >> 3) + ch) * 1024 + (size_t)cp * 16;
    *(uint4*)&echunk[baseo] = lo;        // col cp*2,   j=0..7
    *(uint4*)&echunk[baseo + 8] = hi;    // col cp*2+1, j=0..7
  }
}

// ---------------- fused CSR-aggregate + conv MLP, 64-node tile, pipelined ----------------
// phase A: wave owns 16 nodes (contiguous dst-sorted edge range); chunk-8 walk
//   aligned to global 8-edge chunks; per chunk: 2 b128 e-loads + 8 h gathers +
//   8 scalar src loads; depth-2 pipeline; LDS RMW flush per node.
__global__ void __launch_bounds__(256) k_conv_csr(
    const unsigned short* __restrict__ h16in, const unsigned short* __restrict__ echunk,
    const int* __restrict__ src_s, const int* __restrict__ rowptr,
    const unsigned short* __restrict__ w1t, const float* __restrict__ b1,
    const unsigned short* __restrict__ w2t, const float* __restrict__ b2,
    unsigned short* __restrict__ h16out, int nN) {
  __shared__ __attribute__((aligned(16))) unsigned short zs[64 * LDP];
  __shared__ int rpS[4][20];
  int tid = threadIdx.x;
  int n0 = blockIdx.x * 64;
  int wave = tid >> 6, lane = tid & 63;
  // phase A
  {
    int c2 = lane * 2;
    int wbase = wave * 16;
    int nodeBase = n0 + wbase;
    int nCnt = nN - nodeBase; if (nCnt > 16) nCnt = 16; if (nCnt < 0) nCnt = 0;
#pragma unroll
    for (int i = 0; i < 16; ++i) {
      int n = nodeBase + i;
      unsigned int hv = 0u;
      if (n < nN) hv = *(const unsigned int*)&h16in[(size_t)n * HID + c2];
      *(unsigned int*)&zs[(wbase + i) * LDP + c2] = hv;
    }
    if (lane < 17) {
      int i = (lane < nCnt) ? lane : nCnt;
      rpS[wave][lane] = (nCnt > 0) ? rowptr[nodeBase + i] : 0;
    }
    int eBeg = rpS[wave][0];
    int eEnd = rpS[wave][16];
    if (nCnt > 0 && eBeg < eEnd) {
      float a0 = 0.f, a1 = 0.f;
      int ni = 0;
      int rpEnd = rpS[wave][1];
      int cBeg = eBeg & ~7;
      int sv0[8], sv1[8];
      uint4 ec0[2], ec1[2];
      unsigned int hv0[8], hv1[8];

#define LOAD_S(svv, base)                                              \
  _Pragma("unroll")                                                    \
  for (int i = 0; i < 8; ++i) {                                        \
    int ix = (base) + i;                                               \
    ix = ix < eBeg ? eBeg : (ix >= eEnd ? eEnd - 1 : ix);              \
    svv[i] = src_s[ix];                                                \
  }
#define LOAD_E(ecc, base)                                              \
  { size_t bo = (size_t)((base) >> 3) * 1024 + (size_t)c2 * 8;         \
    ecc[0] = *(const uint4*)&echunk[bo];                               \
    ecc[1] = *(const uint4*)&echunk[bo + 8]; }
#define LOAD_H(hvv, svv)                                               \
  _Pragma("unroll")                                                    \
  for (int i = 0; i < 8; ++i)                                          \
    hvv[i] = *(const unsigned int*)&h16in[(size_t)svv[i] * HID + c2];
#define FLUSH()                                                        \
  { int row = wbase + ni;                                              \
    unsigned int z = *(const unsigned int*)&zs[row * LDP + c2];        \
    float z0 = asf(z << 16) + a0, z1 = asf(z & 0xffff0000u) + a1;      \
    *(unsigned int*)&zs[row * LDP + c2] =                              \
        (unsigned int)f2bf(z0) | ((unsigned int)f2bf(z1) << 16);       \
    a0 = 0.f; a1 = 0.f; }
#define FOLD(ecc, hvv, base)                                           \
  { const unsigned int* wA = (const unsigned int*)&ecc[0];             \
    const unsigned int* wB = (const unsigned int*)&ecc[1];             \
    _Pragma("unroll")                                                  \
    for (int i = 0; i < 8; ++i) {                                      \
      int eg = (base) + i;                                             \
      if (eg >= eBeg && eg < eEnd) {                                   \
        while (eg >= rpEnd) { FLUSH(); ++ni; rpEnd = rpS[wave][ni + 1]; } \
        float e0v = (i & 1) ? asf(wA[i >> 1] & 0xffff0000u)            \
                            : asf(wA[i >> 1] << 16);                   \
        float e1v = (i & 1) ? asf(wB[i >> 1] & 0xffff0000u)            \
                            : asf(wB[i >> 1] << 16);                   \
        a0 += fmaxf(asf(hvv[i] << 16) + e0v, 0.f);                     \
        a1 += fmaxf(asf(hvv[i] & 0xffff0000u) + e1v, 0.f);             \
      }                                                                \
    } }

      LOAD_S(sv0, cBeg)
      LOAD_S(sv1, cBeg + 8)
      LOAD_E(ec0, cBeg)
      LOAD_H(hv0, sv0)
      for (int base = cBeg; base < eEnd; base += 16) {
        if (base + 16 < eEnd) LOAD_S(sv0, base + 16)
        if (base + 8 < eEnd) { LOAD_E(ec1, base + 8) LOAD_H(hv1, sv1) }
        FOLD(ec0, hv0, base)
        if (base + 8 < eEnd) {
          if (base + 24 < eEnd) LOAD_S(sv1, base + 24)
          if (base + 16 < eEnd) { LOAD_E(ec0, base + 16) LOAD_H(hv0, sv0) }
          FOLD(ec1, hv1, base + 8)
        }
      }
      FLUSH()
#undef LOAD_S
#undef LOAD_E
#undef LOAD_H
#undef FLUSH
#undef FOLD
    }
  }
  __syncthreads();
  int l15 = lane & 15, quad = lane >> 4;
  int rbase = (wave >> 1) * 32, nbase = (wave & 1) * 64;
  f32x4 acc[2][4];
#pragma unroll
  for (int i = 0; i < 2; ++i)
#pragma unroll
    for (int j = 0; j < 4; ++j) acc[i][j] = (f32x4){0.f, 0.f, 0.f, 0.f};
  for (int kc = 0; kc < 4; ++kc) {
    int k0 = kc * 32 + quad * 8;
    s16x8 af[2], bf[4];
#pragma unroll
    for (int t = 0; t < 2; ++t)
      af[t] = *(const s16x8*)&zs[(rbase + t * 16 + l15) * LDP + k0];
#pragma unroll
    for (int t = 0; t < 4; ++t)
      bf[t] = *(const s16x8*)&w1t[(size_t)(nbase + t * 16 + l15) * HID + k0];
#pragma unroll
    for (int i = 0; i < 2; ++i)
#pragma unroll
      for (int j = 0; j < 4; ++j)
        acc[i][j] = __builtin_amdgcn_mfma_f32_16x16x32_bf16(af[i], bf[j], acc[i][j], 0, 0, 0);
  }
  __syncthreads();
  {
    float bv[4];
#pragma unroll
    for (int t = 0; t < 4; ++t) bv[t] = b1[nbase + t * 16 + l15];
#pragma unroll
    for (int tr = 0; tr < 2; ++tr)
#pragma unroll
      for (int tc = 0; tc < 4; ++tc)
#pragma unroll
        for (int reg = 0; reg < 4; ++reg) {
          int row = rbase + tr * 16 + quad * 4 + reg;
          int col = nbase + tc * 16 + l15;
          zs[row * LDP + col] = f2bf(fmaxf(acc[tr][tc][reg] + bv[tc], 0.f));
        }
  }
  __syncthreads();
#pragma unroll
  for (int i = 0; i < 2; ++i)
#pragma unroll
    for (int j = 0; j < 4; ++j) acc[i][j] = (f32x4){0.f, 0.f, 0.f, 0.f};
  for (int kc = 0; kc < 4; ++kc) {
    int k0 = kc * 32 + quad * 8;
    s16x8 af[2], bf[4];
#pragma unroll
    for (int t = 0; t < 2; ++t)
      af[t] = *(const s16x8*)&zs[(rbase + t * 16 + l15) * LDP + k0];
#pragma unroll
    for (int t = 0; t < 4; ++t)
      bf[t] = *(const s16x8*)&w2t[(size_t)(nbase + t * 16 + l15) * HID + k0];
#pragma unroll
    for (int i = 0; i < 2; ++i)
#pragma unroll
      for (int j = 0; j < 4; ++j)
        acc[i][j] = __builtin_amdgcn_mfma_f32_16x16x32_bf16(af[i], bf[j], acc[i][j], 0, 0, 0);
  }
  {
    float bv[4];
#pragma unroll
    for (int t = 0; t < 4; ++t) bv[t] = b2[nbase + t * 16 + l15];
#pragma unroll
    for (int tr = 0; tr < 2; ++tr)
#pragma unroll
      for (int reg = 0; reg < 4; ++reg) {
        int grow = n0 + rbase + tr * 16 + quad * 4 + reg;
        if (grow < nN) {
#pragma unroll
          for (int tc = 0; tc < 4; ++tc) {
            int col = nbase + tc * 16 + l15;
            h16out[(size_t)grow * HID + col] = f2bf(fmaxf(acc[tr][tc][reg] + bv[tc], 0.f));
          }
        }
      }
  }
}

// ---------------- counts ----------------
__global__ void k_counts(const int* __restrict__ batch, int* __restrict__ cnts, int nN) {
  int i = blockIdx.x * blockDim.x + threadIdx.x;
  if (i < nN) atomicAdd(&cnts[batch[i]], 1);
}

// ---------------- segment-reduced pool (batch sorted) ----------------
__global__ void __launch_bounds__(256) k_pool2(
    const unsigned short* __restrict__ h16, const int* __restrict__ batch,
    float* __restrict__ g, int nN) {
  __shared__ int bL[128];
  int tid = threadIdx.x;
  int n0 = blockIdx.x * 128;
  if (tid < 128) {
    int n = n0 + tid;
    bL[tid] = (n < nN) ? batch[n] : -1;
  }
  __syncthreads();
  int half = tid >> 7, col = tid & 127;
  int rs = half * 64;
  int cur = -1;
  float s = 0.f;
  for (int r = rs; r < rs + 64; ++r) {
    int b = bL[r];
    float v = (b >= 0) ? bf2f((unsigned int)h16[(size_t)(n0 + r) * HID + col]) : 0.f;
    if (b != cur) {
      if (cur >= 0) atomicAdd(&g[(size_t)cur * HID + col], s);
      cur = b; s = v;
    } else s += v;
  }
  if (cur >= 0) atomicAdd(&g[(size_t)cur * HID + col], s);
}

// ---------------- heads ----------------
__global__ void __launch_bounds__(128) k_head(
    const float* __restrict__ g, const int* __restrict__ counts,
    const float* __restrict__ clw1, const float* __restrict__ clb1,
    const float* __restrict__ clw2, const float* __restrict__ clb2,
    const float* __restrict__ rw1, const float* __restrict__ rb1,
    const float* __restrict__ rw2, const float* __restrict__ rb2,
    float* __restrict__ out, int nG) {
  __shared__ float gs[HID];
  int b = blockIdx.x;
  int tid = threadIdx.x;
  float cnt = fmaxf((float)counts[b], 1.f);
  gs[tid] = g[b * HID + tid] / cnt;
  __syncthreads();
  int wave = tid >> 6, lane = tid & 63;
  const float* w1 = wave ? rw1 : clw1;
  const float* b1 = wave ? rb1 : clb1;
  const float* w2 = wave ? rw2 : clw2;
  const float* b2 = wave ? rb2 : clb2;
  float acc = b1[lane];
  for (int k = 0; k < HID; ++k) acc += gs[k] * w1[k * 64 + lane];
  acc = fmaxf(acc, 0.f) * w2[lane];
#pragma unroll
  for (int off = 32; off; off >>= 1) acc += __shfl_down(acc, off);
  if (lane == 0) out[wave * nG + b] = acc + b2[0];
}

extern "C" void kernel_launch(void* const* d_in, const int* in_sizes, int n_in,
                              void* d_out, int out_size, void* d_ws, size_t ws_size,
                              hipStream_t stream) {
  const float* x      = (const float*)d_in[0];
  const float* ea     = (const float*)d_in[1];
  const int*   eidx   = (const int*)d_in[2];
  const int*   batch  = (const int*)d_in[3];
  const float* node_w = (const float*)d_in[4];
  const float* node_b = (const float*)d_in[5];
  const float* ew1    = (const float*)d_in[6];
  const float* eb1    = (const float*)d_in[7];
  const float* ew2    = (const float*)d_in[8];
  const float* eb2    = (const float*)d_in[9];
  const float* cw1    = (const float*)d_in[10];
  const float* cb1    = (const float*)d_in[11];
  const float* cw2    = (const float*)d_in[12];
  const float* cb2    = (const float*)d_in[13];
  const float* clw1   = (const float*)d_in[14];
  const float* clb1   = (const float*)d_in[15];
  const float* clw2   = (const float*)d_in[16];
  const float* clb2   = (const float*)d_in[17];
  const float* rw1    = (const float*)d_in[18];
  const float* rb1    = (const float*)d_in[19];
  const float* rw2    = (const float*)d_in[20];
  const float* rb2    = (const float*)d_in[21];
  float* out = (float*)d_out;

  int nN = in_sizes[3];        // 100000
  int nE = in_sizes[2] / 2;    // 640000 (divisible by 128)
  int nG = out_size / 2;       // 2048
  const int* src = eidx;
  const int* dst = eidx + nE;

  int NB = (nN + 255) / 256;
  int bins = NB * 256;

  // ---- workspace (~223 MB) ----
  size_t hN = (size_t)nN * HID;
  size_t gN = (size_t)nG * HID;
  float* g    = (float*)d_ws;                       // gN
  int*   cnts = (int*)(g + gN);                     // nG
  unsigned short* wT   = (unsigned short*)(cnts + nG);  // 7*16384
  unsigned short* h16a = wT + 7 * 16384;            // hN
  unsigned short* h16b = h16a + hN;                 // hN
  int* deg    = (int*)(h16b + hN);                  // bins
  int* cursor = deg + bins;                         // bins
  int* rowptr = cursor + bins;                      // bins
  int* bsum   = rowptr + bins;                      // 512
  int* bsumx  = bsum + 512;                         // 512
  int* src_s  = bsumx + 512;                        // nE
  int* esort  = src_s + nE;                         // nE
  unsigned short* echunk = (unsigned short*)(esort + nE);  // nE*128

  // ---- counting sort of edges by dst (builds CSR rowptr + permutation) ----
  k_zero4<<<(int)((bins / 4 + 255) / 256), 256, 0, stream>>>((float4*)deg, bins / 4);
  k_hist<<<(nE + 255) / 256, 256, 0, stream>>>(dst, deg, nE);
  k_scanA<<<NB, 256, 0, stream>>>(deg, bsum);
  k_scanB<<<1, 512, 0, stream>>>(bsum, bsumx, NB);
  k_scanC<<<NB, 256, 0, stream>>>(deg, bsumx, cursor, rowptr);
  k_scatter<<<(nE + 255) / 256, 256, 0, stream>>>(src, dst, cursor, src_s, esort, nE);

  k_prep_w<<<(7 * 16384 + 255) / 256, 256, 0, stream>>>(ew2, cw1, cw2, wT);
  k_edge_gemm<<<nE / 128, 256, 0, stream>>>(ea, esort, ew1, eb1, wT, eb2, echunk, nE);
  k_node_enc<<<(nN * HID + 255) / 256, 256, 0, stream>>>(x, node_w, node_b, h16a, nN);

  // ping-pong: A->B, B->A, A->B
  unsigned short* hin  = h16a;
  unsigned short* hout = h16b;
  for (int l = 0; l < 3; ++l) {
    k_conv_csr<<<(nN + 63) / 64, 256, 0, stream>>>(
        hin, echunk, src_s, rowptr,
        wT + (size_t)(1 + l) * 16384, cb1 + (size_t)l * HID,
        wT + (size_t)(4 + l) * 16384, cb2 + (size_t)l * HID, hout, nN);
    unsigned short* t = hin; hin = hout; hout = t;
  }

  k_zero4<<<(int)(((gN + nG) / 4 + 255) / 256), 256, 0, stream>>>((float4*)g, (gN + nG) / 4);
  k_counts<<<(nN + 255) / 256, 256, 0, stream>>>(batch, cnts, nN);
  k_pool2<<<(nN + 127) / 128, 256, 0, stream>>>(hin, batch, g, nN);
  k_head<<<nG, 128, 0, stream>>>(g, cnts, clw1, clb1, clw2, clb2,
                                 rw1, rb1, rw2, rb2, out, nG);
}

// Round 15
// 654.949 us; speedup vs baseline: 1.0428x; 1.0428x over previous
//
#include <hip/hip_runtime.h>

#define HID 128
#define LDP 136   // padded LDS row stride in bf16 elems (272 B)

typedef short s16x8 __attribute__((ext_vector_type(8)));
typedef float f32x4 __attribute__((ext_vector_type(4)));

__device__ __forceinline__ float bf2f(unsigned int u) {
  union { unsigned int i; float f; } v; v.i = u << 16; return v.f;
}
__device__ __forceinline__ float asf(unsigned int u) {
  union { unsigned int i; float f; } v; v.i = u; return v.f;
}
__device__ __forceinline__ unsigned short f2bf(float f) {
  union { float f; unsigned int i; } v; v.f = f;
  unsigned int r = v.i + 0x7fffu + ((v.i >> 16) & 1u);
  return (unsigned short)(r >> 16);
}

// ---------------- zero fill (vectorized) ----------------
__global__ void k_zero4(float4* __restrict__ p, size_t n4) {
  size_t i = (size_t)blockIdx.x * blockDim.x + threadIdx.x;
  if (i < n4) p[i] = (float4){0.f, 0.f, 0.f, 0.f};
}

// ---------------- counting sort ----------------
__global__ void k_hist(const int* __restrict__ dst, int* __restrict__ deg, int nE) {
  int e = blockIdx.x * blockDim.x + threadIdx.x;
  if (e < nE) atomicAdd(&deg[dst[e]], 1);
}

__global__ void k_scanA(const int* __restrict__ deg, int* __restrict__ bsum) {
  __shared__ int ss[256];
  int t = threadIdx.x;
  ss[t] = deg[blockIdx.x * 256 + t];
  __syncthreads();
  for (int off = 128; off; off >>= 1) {
    if (t < off) ss[t] += ss[t + off];
    __syncthreads();
  }
  if (t == 0) bsum[blockIdx.x] = ss[0];
}

__global__ void k_scanB(const int* __restrict__ bsum, int* __restrict__ bsumx, int NB) {
  __shared__ int sd[512];
  int t = threadIdx.x;
  int v = (t < NB) ? bsum[t] : 0;
  sd[t] = v;
  __syncthreads();
  for (int off = 1; off < 512; off <<= 1) {
    int a = (t >= off) ? sd[t - off] : 0;
    __syncthreads();
    sd[t] += a;
    __syncthreads();
  }
  if (t < NB) bsumx[t] = sd[t] - v;
}

// exclusive scan to BOTH cursor (mutated by scatter) and rowptr (kept)
__global__ void k_scanC(const int* __restrict__ deg, const int* __restrict__ bsumx,
                        int* __restrict__ cursor, int* __restrict__ rowptr) {
  __shared__ int ss[256];
  int t = threadIdx.x, i = blockIdx.x * 256 + t;
  int v = deg[i];
  ss[t] = v;
  __syncthreads();
  for (int off = 1; off < 256; off <<= 1) {
    int a = (t >= off) ? ss[t - off] : 0;
    __syncthreads();
    ss[t] += a;
    __syncthreads();
  }
  int ex = ss[t] - v + bsumx[blockIdx.x];
  cursor[i] = ex;
  rowptr[i] = ex;
}

__global__ void k_scatter(const int* __restrict__ src, const int* __restrict__ dst,
                          const float* __restrict__ ea, int* __restrict__ cursor,
                          int* __restrict__ src_s, float* __restrict__ ea_s, int nE) {
  int e = blockIdx.x * blockDim.x + threadIdx.x;
  if (e >= nE) return;
  int d = dst[e];
  int pos = atomicAdd(&cursor[d], 1);
  src_s[pos] = src[e];
  ea_s[(size_t)pos * 3 + 0] = ea[(size_t)e * 3 + 0];
  ea_s[(size_t)pos * 3 + 1] = ea[(size_t)e * 3 + 1];
  ea_s[(size_t)pos * 3 + 2] = ea[(size_t)e * 3 + 2];
}

// ---------------- transpose weights to bf16 ----------------
__global__ void k_prep_w(const float* __restrict__ ew2, const float* __restrict__ cw1,
                         const float* __restrict__ cw2, unsigned short* __restrict__ wT) {
  int idx = blockIdx.x * blockDim.x + threadIdx.x;
  if (idx >= 7 * 16384) return;
  int m = idx >> 14, i = idx & 16383;
  int n = i >> 7, k = i & 127;
  const float* s = (m == 0) ? ew2 : (m <= 3 ? cw1 + (size_t)(m - 1) * 16384
                                            : cw2 + (size_t)(m - 4) * 16384);
  wT[idx] = f2bf(s[k * 128 + n]);
}

// ---------------- node encoder ----------------
__global__ void k_node_enc(const float* __restrict__ x, const float* __restrict__ w,
                           const float* __restrict__ b, unsigned short* __restrict__ h16, int nN) {
  int idx = blockIdx.x * blockDim.x + threadIdx.x;
  if (idx >= nN * HID) return;
  int i = idx >> 7, j = idx & 127;
  float acc = b[j];
  const float* xr = x + (size_t)i * 7;
#pragma unroll
  for (int k = 0; k < 7; ++k) acc += xr[k] * w[k * HID + j];
  h16[idx] = f2bf(acc);
}

// ---------------- one-time edge encoder GEMM -> e16 (direct C/D stores) ----------------
__global__ void __launch_bounds__(256) k_edge_gemm(
    const float* __restrict__ ea_s, const float* __restrict__ ew1, const float* __restrict__ eb1,
    const unsigned short* __restrict__ w2t, const float* __restrict__ eb2,
    unsigned short* __restrict__ e16, int nE) {
  __shared__ __attribute__((aligned(16))) unsigned short ts1[128 * LDP];
  __shared__ float eaL[384];
  int tid = threadIdx.x;
  int e0 = blockIdx.x * 128;                      // nE % 128 == 0
  for (int i = tid; i < 384; i += 256) eaL[i] = ea_s[(size_t)e0 * 3 + i];
  __syncthreads();
  {
    int j = tid & 127, r0 = (tid >> 7) * 64;
    float wa = ew1[j], wb = ew1[HID + j], wc = ew1[2 * HID + j], bj = eb1[j];
    for (int r = r0; r < r0 + 64; ++r) {
      float a = bj + eaL[r * 3] * wa + eaL[r * 3 + 1] * wb + eaL[r * 3 + 2] * wc;
      ts1[r * LDP + j] = f2bf(fmaxf(a, 0.f));
    }
  }
  __syncthreads();
  int wave = tid >> 6, lane = tid & 63;
  int l15 = lane & 15, quad = lane >> 4;
  int rbase = (wave >> 1) * 64, nbase = (wave & 1) * 64;
  f32x4 acc[4][4];
#pragma unroll
  for (int i = 0; i < 4; ++i)
#pragma unroll
    for (int j = 0; j < 4; ++j) acc[i][j] = (f32x4){0.f, 0.f, 0.f, 0.f};
  for (int kc = 0; kc < 4; ++kc) {
    int k0 = kc * 32 + quad * 8;
    s16x8 af[4], bf[4];
#pragma unroll
    for (int t = 0; t < 4; ++t)
      af[t] = *(const s16x8*)&ts1[(rbase + t * 16 + l15) * LDP + k0];
#pragma unroll
    for (int t = 0; t < 4; ++t)
      bf[t] = *(const s16x8*)&w2t[(size_t)(nbase + t * 16 + l15) * HID + k0];
#pragma unroll
    for (int i = 0; i < 4; ++i)
#pragma unroll
      for (int j = 0; j < 4; ++j)
        acc[i][j] = __builtin_amdgcn_mfma_f32_16x16x32_bf16(af[i], bf[j], acc[i][j], 0, 0, 0);
  }
  float ebv[4];
#pragma unroll
  for (int t = 0; t < 4; ++t) ebv[t] = eb2[nbase + t * 16 + l15];
#pragma unroll
  for (int tr = 0; tr < 4; ++tr)
#pragma unroll
    for (int reg = 0; reg < 4; ++reg) {
      int row = rbase + tr * 16 + quad * 4 + reg;   // C/D: col=lane&15, row=quad*4+reg
#pragma unroll
      for (int tc = 0; tc < 4; ++tc) {
        int col = nbase + tc * 16 + l15;
        e16[(size_t)(e0 + row) * HID + col] = f2bf(acc[tr][tc][reg] + ebv[tc]);
      }
    }
}

// ---------------- fused CSR-aggregate + conv MLP, 32-node tile, pipelined ----------------
// 4 waves; wave owns 8 nodes (~51 edges, contiguous dst-sorted range).
// phase A: depth-2 pipelined chunk-8 walk (src -> e16/h16 gathers in flight),
//   node boundaries from rowptr cached in LDS; LDS RMW flush per node;
//   zs pre-init = h covers degree-0 nodes.
// GEMM: M=32; wave = 16 rows x 64 cols (acc[1][4]).
__global__ void __launch_bounds__(256) k_conv_csr(
    const unsigned short* __restrict__ h16in, const unsigned short* __restrict__ e16,
    const int* __restrict__ src_s, const int* __restrict__ rowptr,
    const unsigned short* __restrict__ w1t, const float* __restrict__ b1,
    const unsigned short* __restrict__ w2t, const float* __restrict__ b2,
    unsigned short* __restrict__ h16out, int nN) {
  __shared__ __attribute__((aligned(16))) unsigned short zs[32 * LDP];
  __shared__ int rpS[4][12];
  int tid = threadIdx.x;
  int n0 = blockIdx.x * 32;
  int wave = tid >> 6, lane = tid & 63;
  // phase A
  {
    int c2 = lane * 2;
    int wbase = wave * 8;
    int nodeBase = n0 + wbase;
    int nCnt = nN - nodeBase; if (nCnt > 8) nCnt = 8; if (nCnt < 0) nCnt = 0;
#pragma unroll
    for (int i = 0; i < 8; ++i) {
      int n = nodeBase + i;
      unsigned int hv = 0u;
      if (n < nN) hv = *(const unsigned int*)&h16in[(size_t)n * HID + c2];
      *(unsigned int*)&zs[(wbase + i) * LDP + c2] = hv;
    }
    if (lane < 9) {
      int i = (lane < nCnt) ? lane : nCnt;
      rpS[wave][lane] = (nCnt > 0) ? rowptr[nodeBase + i] : 0;
    }
    int eBeg = rpS[wave][0];
    int eEnd = rpS[wave][8];
    if (nCnt > 0 && eBeg < eEnd) {
      float a0 = 0.f, a1 = 0.f;
      int ni = 0;
      int rpEnd = rpS[wave][1];
      int sv0[8], sv1[8];
      unsigned int ev0[8], hv0[8], ev1[8], hv1[8];

#define LOAD_S(svv, base)                                            \
  _Pragma("unroll")                                                  \
  for (int i = 0; i < 8; ++i) {                                      \
    int ix = (base) + i; if (ix >= eEnd) ix = eEnd - 1;              \
    svv[i] = src_s[ix];                                              \
  }
#define LOAD_EH(evv, hvv, svv, base)                                 \
  _Pragma("unroll")                                                  \
  for (int i = 0; i < 8; ++i) {                                      \
    int ix = (base) + i; if (ix >= eEnd) ix = eEnd - 1;              \
    evv[i] = *(const unsigned int*)&e16[(size_t)ix * HID + c2];      \
    hvv[i] = *(const unsigned int*)&h16in[(size_t)svv[i] * HID + c2];\
  }
#define FLUSH()                                                      \
  { int row = wbase + ni;                                            \
    unsigned int z = *(const unsigned int*)&zs[row * LDP + c2];      \
    float z0 = asf(z << 16) + a0, z1 = asf(z & 0xffff0000u) + a1;    \
    *(unsigned int*)&zs[row * LDP + c2] =                            \
        (unsigned int)f2bf(z0) | ((unsigned int)f2bf(z1) << 16);     \
    a0 = 0.f; a1 = 0.f; }
#define FOLD(evv, hvv, base)                                         \
  { int cnt = eEnd - (base); if (cnt > 8) cnt = 8;                   \
    _Pragma("unroll")                                                \
    for (int i = 0; i < 8; ++i) if (i < cnt) {                       \
      int eg = (base) + i;                                           \
      while (eg >= rpEnd) { FLUSH(); ++ni; rpEnd = rpS[wave][ni + 1]; } \
      a0 += fmaxf(asf(hvv[i] << 16) + asf(evv[i] << 16), 0.f);       \
      a1 += fmaxf(asf(hvv[i] & 0xffff0000u) + asf(evv[i] & 0xffff0000u), 0.f); \
    } }

      LOAD_S(sv0, eBeg)
      LOAD_S(sv1, eBeg + 8)
      LOAD_EH(ev0, hv0, sv0, eBeg)
      for (int e = eBeg; e < eEnd; e += 16) {
        if (e + 16 < eEnd) LOAD_S(sv0, e + 16)
        if (e + 8 < eEnd)  LOAD_EH(ev1, hv1, sv1, e + 8)
        FOLD(ev0, hv0, e)
        if (e + 8 < eEnd) {
          if (e + 24 < eEnd) LOAD_S(sv1, e + 24)
          if (e + 16 < eEnd) LOAD_EH(ev0, hv0, sv0, e + 16)
          FOLD(ev1, hv1, e + 8)
        }
      }
      FLUSH()
#undef LOAD_S
#undef LOAD_EH
#undef FLUSH
#undef FOLD
    }
  }
  __syncthreads();
  int l15 = lane & 15, quad = lane >> 4;
  int rbase = (wave >> 1) * 16, nbase = (wave & 1) * 64;
  f32x4 acc[4];
#pragma unroll
  for (int j = 0; j < 4; ++j) acc[j] = (f32x4){0.f, 0.f, 0.f, 0.f};
  for (int kc = 0; kc < 4; ++kc) {
    int k0 = kc * 32 + quad * 8;
    s16x8 af, bf[4];
    af = *(const s16x8*)&zs[(rbase + l15) * LDP + k0];
#pragma unroll
    for (int t = 0; t < 4; ++t)
      bf[t] = *(const s16x8*)&w1t[(size_t)(nbase + t * 16 + l15) * HID + k0];
#pragma unroll
    for (int j = 0; j < 4; ++j)
      acc[j] = __builtin_amdgcn_mfma_f32_16x16x32_bf16(af, bf[j], acc[j], 0, 0, 0);
  }
  __syncthreads();
  {
    float bv[4];
#pragma unroll
    for (int t = 0; t < 4; ++t) bv[t] = b1[nbase + t * 16 + l15];
#pragma unroll
    for (int tc = 0; tc < 4; ++tc)
#pragma unroll
      for (int reg = 0; reg < 4; ++reg) {
        int row = rbase + quad * 4 + reg;
        int col = nbase + tc * 16 + l15;
        zs[row * LDP + col] = f2bf(fmaxf(acc[tc][reg] + bv[tc], 0.f));
      }
  }
  __syncthreads();
#pragma unroll
  for (int j = 0; j < 4; ++j) acc[j] = (f32x4){0.f, 0.f, 0.f, 0.f};
  for (int kc = 0; kc < 4; ++kc) {
    int k0 = kc * 32 + quad * 8;
    s16x8 af, bf[4];
    af = *(const s16x8*)&zs[(rbase + l15) * LDP + k0];
#pragma unroll
    for (int t = 0; t < 4; ++t)
      bf[t] = *(const s16x8*)&w2t[(size_t)(nbase + t * 16 + l15) * HID + k0];
#pragma unroll
    for (int j = 0; j < 4; ++j)
      acc[j] = __builtin_amdgcn_mfma_f32_16x16x32_bf16(af, bf[j], acc[j], 0, 0, 0);
  }
  {
    float bv[4];
#pragma unroll
    for (int t = 0; t < 4; ++t) bv[t] = b2[nbase + t * 16 + l15];
#pragma unroll
    for (int reg = 0; reg < 4; ++reg) {
      int grow = n0 + rbase + quad * 4 + reg;
      if (grow < nN) {
#pragma unroll
        for (int tc = 0; tc < 4; ++tc) {
          int col = nbase + tc * 16 + l15;
          h16out[(size_t)grow * HID + col] = f2bf(fmaxf(acc[tc][reg] + bv[tc], 0.f));
        }
      }
    }
  }
}

// ---------------- counts ----------------
__global__ void k_counts(const int* __restrict__ batch, int* __restrict__ cnts, int nN) {
  int i = blockIdx.x * blockDim.x + threadIdx.x;
  if (i < nN) atomicAdd(&cnts[batch[i]], 1);
}

// ---------------- segment-reduced pool (batch sorted) ----------------
__global__ void __launch_bounds__(256) k_pool2(
    const unsigned short* __restrict__ h16, const int* __restrict__ batch,
    float* __restrict__ g, int nN) {
  __shared__ int bL[128];
  int tid = threadIdx.x;
  int n0 = blockIdx.x * 128;
  if (tid < 128) {
    int n = n0 + tid;
    bL[tid] = (n < nN) ? batch[n] : -1;
  }
  __syncthreads();
  int half = tid >> 7, col = tid & 127;
  int rs = half * 64;
  int cur = -1;
  float s = 0.f;
  for (int r = rs; r < rs + 64; ++r) {
    int b = bL[r];
    float v = (b >= 0) ? bf2f((unsigned int)h16[(size_t)(n0 + r) * HID + col]) : 0.f;
    if (b != cur) {
      if (cur >= 0) atomicAdd(&g[(size_t)cur * HID + col], s);
      cur = b; s = v;
    } else s += v;
  }
  if (cur >= 0) atomicAdd(&g[(size_t)cur * HID + col], s);
}

// ---------------- heads ----------------
__global__ void __launch_bounds__(128) k_head(
    const float* __restrict__ g, const int* __restrict__ counts,
    const float* __restrict__ clw1, const float* __restrict__ clb1,
    const float* __restrict__ clw2, const float* __restrict__ clb2,
    const float* __restrict__ rw1, const float* __restrict__ rb1,
    const float* __restrict__ rw2, const float* __restrict__ rb2,
    float* __restrict__ out, int nG) {
  __shared__ float gs[HID];
  int b = blockIdx.x;
  int tid = threadIdx.x;
  float cnt = fmaxf((float)counts[b], 1.f);
  gs[tid] = g[b * HID + tid] / cnt;
  __syncthreads();
  int wave = tid >> 6, lane = tid & 63;
  const float* w1 = wave ? rw1 : clw1;
  const float* b1 = wave ? rb1 : clb1;
  const float* w2 = wave ? rw2 : clw2;
  const float* b2 = wave ? rb2 : clb2;
  float acc = b1[lane];
  for (int k = 0; k < HID; ++k) acc += gs[k] * w1[k * 64 + lane];
  acc = fmaxf(acc, 0.f) * w2[lane];
#pragma unroll
  for (int off = 32; off; off >>= 1) acc += __shfl_down(acc, off);
  if (lane == 0) out[wave * nG + b] = acc + b2[0];
}

extern "C" void kernel_launch(void* const* d_in, const int* in_sizes, int n_in,
                              void* d_out, int out_size, void* d_ws, size_t ws_size,
                              hipStream_t stream) {
  const float* x      = (const float*)d_in[0];
  const float* ea     = (const float*)d_in[1];
  const int*   eidx   = (const int*)d_in[2];
  const int*   batch  = (const int*)d_in[3];
  const float* node_w = (const float*)d_in[4];
  const float* node_b = (const float*)d_in[5];
  const float* ew1    = (const float*)d_in[6];
  const float* eb1    = (const float*)d_in[7];
  const float* ew2    = (const float*)d_in[8];
  const float* eb2    = (const float*)d_in[9];
  const float* cw1    = (const float*)d_in[10];
  const float* cb1    = (const float*)d_in[11];
  const float* cw2    = (const float*)d_in[12];
  const float* cb2    = (const float*)d_in[13];
  const float* clw1   = (const float*)d_in[14];
  const float* clb1   = (const float*)d_in[15];
  const float* clw2   = (const float*)d_in[16];
  const float* clb2   = (const float*)d_in[17];
  const float* rw1    = (const float*)d_in[18];
  const float* rb1    = (const float*)d_in[19];
  const float* rw2    = (const float*)d_in[20];
  const float* rb2    = (const float*)d_in[21];
  float* out = (float*)d_out;

  int nN = in_sizes[3];        // 100000
  int nE = in_sizes[2] / 2;    // 640000 (divisible by 128)
  int nG = out_size / 2;       // 2048
  const int* src = eidx;
  const int* dst = eidx + nE;

  int NB = (nN + 255) / 256;
  int bins = NB * 256;

  // ---- workspace (~231 MB) ----
  size_t hN = (size_t)nN * HID;
  size_t gN = (size_t)nG * HID;
  float* g    = (float*)d_ws;                       // gN
  int*   cnts = (int*)(g + gN);                     // nG
  unsigned short* wT   = (unsigned short*)(cnts + nG);  // 7*16384
  unsigned short* h16a = wT + 7 * 16384;            // hN
  unsigned short* h16b = h16a + hN;                 // hN
  int* deg    = (int*)(h16b + hN);                  // bins
  int* cursor = deg + bins;                         // bins
  int* rowptr = cursor + bins;                      // bins
  int* bsum   = rowptr + bins;                      // 512
  int* bsumx  = bsum + 512;                         // 512
  int* src_s  = bsumx + 512;                        // nE
  float* ea_s = (float*)(src_s + nE);               // 3*nE
  unsigned short* e16 = (unsigned short*)(ea_s + (size_t)3 * nE);  // nE*128

  // ---- counting sort of edges by dst (also builds CSR rowptr) ----
  k_zero4<<<(int)((bins / 4 + 255) / 256), 256, 0, stream>>>((float4*)deg, bins / 4);
  k_hist<<<(nE + 255) / 256, 256, 0, stream>>>(dst, deg, nE);
  k_scanA<<<NB, 256, 0, stream>>>(deg, bsum);
  k_scanB<<<1, 512, 0, stream>>>(bsum, bsumx, NB);
  k_scanC<<<NB, 256, 0, stream>>>(deg, bsumx, cursor, rowptr);
  k_scatter<<<(nE + 255) / 256, 256, 0, stream>>>(src, dst, ea, cursor, src_s, ea_s, nE);

  k_prep_w<<<(7 * 16384 + 255) / 256, 256, 0, stream>>>(ew2, cw1, cw2, wT);
  k_edge_gemm<<<nE / 128, 256, 0, stream>>>(ea_s, ew1, eb1, wT, eb2, e16, nE);
  k_node_enc<<<(nN * HID + 255) / 256, 256, 0, stream>>>(x, node_w, node_b, h16a, nN);

  // ping-pong: A->B, B->A, A->B  (final in h16b)
  unsigned short* hin  = h16a;
  unsigned short* hout = h16b;
  for (int l = 0; l < 3; ++l) {
    k_conv_csr<<<(nN + 31) / 32, 256, 0, stream>>>(
        hin, e16, src_s, rowptr,
        wT + (size_t)(1 + l) * 16384, cb1 + (size_t)l * HID,
        wT + (size_t)(4 + l) * 16384, cb2 + (size_t)l * HID, hout, nN);
    unsigned short* t = hin; hin = hout; hout = t;
  }

  k_zero4<<<(int)(((gN + nG) / 4 + 255) / 256), 256, 0, stream>>>((float4*)g, (gN + nG) / 4);
  k_counts<<<(nN + 255) / 256, 256, 0, stream>>>(batch, cnts, nN);
  k_pool2<<<(nN + 127) / 128, 256, 0, stream>>>(hin, batch, g, nN);
  k_head<<<nG, 128, 0, stream>>>(g, cnts, clw1, clb1, clw2, clb2,
                                 rw1, rb1, rw2, rb2, out, nG);
}

// Round 16
// 630.990 us; speedup vs baseline: 1.0823x; 1.0380x over previous
//
#include <hip/hip_runtime.h>

#define HID 128
#define LDP 136   // padded LDS row stride in bf16 elems (272 B)

typedef short s16x8 __attribute__((ext_vector_type(8)));
typedef float f32x4 __attribute__((ext_vector_type(4)));

__device__ __forceinline__ float bf2f(unsigned int u) {
  union { unsigned int i; float f; } v; v.i = u << 16; return v.f;
}
__device__ __forceinline__ float asf(unsigned int u) {
  union { unsigned int i; float f; } v; v.i = u; return v.f;
}
__device__ __forceinline__ unsigned short f2bf(float f) {
  union { float f; unsigned int i; } v; v.f = f;
  unsigned int r = v.i + 0x7fffu + ((v.i >> 16) & 1u);
  return (unsigned short)(r >> 16);
}

// ---------------- zero fill (vectorized) ----------------
__global__ void k_zero4(float4* __restrict__ p, size_t n4) {
  size_t i = (size_t)blockIdx.x * blockDim.x + threadIdx.x;
  if (i < n4) p[i] = (float4){0.f, 0.f, 0.f, 0.f};
}

// ---------------- counting sort ----------------
__global__ void k_hist(const int* __restrict__ dst, int* __restrict__ deg, int nE) {
  int e = blockIdx.x * blockDim.x + threadIdx.x;
  if (e < nE) atomicAdd(&deg[dst[e]], 1);
}

__global__ void k_scanA(const int* __restrict__ deg, int* __restrict__ bsum) {
  __shared__ int ss[256];
  int t = threadIdx.x;
  ss[t] = deg[blockIdx.x * 256 + t];
  __syncthreads();
  for (int off = 128; off; off >>= 1) {
    if (t < off) ss[t] += ss[t + off];
    __syncthreads();
  }
  if (t == 0) bsum[blockIdx.x] = ss[0];
}

__global__ void k_scanB(const int* __restrict__ bsum, int* __restrict__ bsumx, int NB) {
  __shared__ int sd[512];
  int t = threadIdx.x;
  int v = (t < NB) ? bsum[t] : 0;
  sd[t] = v;
  __syncthreads();
  for (int off = 1; off < 512; off <<= 1) {
    int a = (t >= off) ? sd[t - off] : 0;
    __syncthreads();
    sd[t] += a;
    __syncthreads();
  }
  if (t < NB) bsumx[t] = sd[t] - v;
}

// exclusive scan to BOTH cursor (mutated by scatter) and rowptr (kept)
__global__ void k_scanC(const int* __restrict__ deg, const int* __restrict__ bsumx,
                        int* __restrict__ cursor, int* __restrict__ rowptr) {
  __shared__ int ss[256];
  int t = threadIdx.x, i = blockIdx.x * 256 + t;
  int v = deg[i];
  ss[t] = v;
  __syncthreads();
  for (int off = 1; off < 256; off <<= 1) {
    int a = (t >= off) ? ss[t - off] : 0;
    __syncthreads();
    ss[t] += a;
    __syncthreads();
  }
  int ex = ss[t] - v + bsumx[blockIdx.x];
  cursor[i] = ex;
  rowptr[i] = ex;
}

__global__ void k_scatter(const int* __restrict__ src, const int* __restrict__ dst,
                          const float* __restrict__ ea, int* __restrict__ cursor,
                          int* __restrict__ src_s, float* __restrict__ ea_s, int nE) {
  int e = blockIdx.x * blockDim.x + threadIdx.x;
  if (e >= nE) return;
  int d = dst[e];
  int pos = atomicAdd(&cursor[d], 1);
  src_s[pos] = src[e];
  ea_s[(size_t)pos * 3 + 0] = ea[(size_t)e * 3 + 0];
  ea_s[(size_t)pos * 3 + 1] = ea[(size_t)e * 3 + 1];
  ea_s[(size_t)pos * 3 + 2] = ea[(size_t)e * 3 + 2];
}

// ---------------- transpose weights to bf16 ----------------
__global__ void k_prep_w(const float* __restrict__ ew2, const float* __restrict__ cw1,
                         const float* __restrict__ cw2, unsigned short* __restrict__ wT) {
  int idx = blockIdx.x * blockDim.x + threadIdx.x;
  if (idx >= 7 * 16384) return;
  int m = idx >> 14, i = idx & 16383;
  int n = i >> 7, k = i & 127;
  const float* s = (m == 0) ? ew2 : (m <= 3 ? cw1 + (size_t)(m - 1) * 16384
                                            : cw2 + (size_t)(m - 4) * 16384);
  wT[idx] = f2bf(s[k * 128 + n]);
}

// ---------------- node encoder ----------------
__global__ void k_node_enc(const float* __restrict__ x, const float* __restrict__ w,
                           const float* __restrict__ b, unsigned short* __restrict__ h16, int nN) {
  int idx = blockIdx.x * blockDim.x + threadIdx.x;
  if (idx >= nN * HID) return;
  int i = idx >> 7, j = idx & 127;
  float acc = b[j];
  const float* xr = x + (size_t)i * 7;
#pragma unroll
  for (int k = 0; k < 7; ++k) acc += xr[k] * w[k * HID + j];
  h16[idx] = f2bf(acc);
}

// ---------------- one-time edge encoder GEMM -> e16 (direct C/D stores) ----------------
__global__ void __launch_bounds__(256) k_edge_gemm(
    const float* __restrict__ ea_s, const float* __restrict__ ew1, const float* __restrict__ eb1,
    const unsigned short* __restrict__ w2t, const float* __restrict__ eb2,
    unsigned short* __restrict__ e16, int nE) {
  __shared__ __attribute__((aligned(16))) unsigned short ts1[128 * LDP];
  __shared__ float eaL[384];
  int tid = threadIdx.x;
  int e0 = blockIdx.x * 128;                      // nE % 128 == 0
  for (int i = tid; i < 384; i += 256) eaL[i] = ea_s[(size_t)e0 * 3 + i];
  __syncthreads();
  {
    int j = tid & 127, r0 = (tid >> 7) * 64;
    float wa = ew1[j], wb = ew1[HID + j], wc = ew1[2 * HID + j], bj = eb1[j];
    for (int r = r0; r < r0 + 64; ++r) {
      float a = bj + eaL[r * 3] * wa + eaL[r * 3 + 1] * wb + eaL[r * 3 + 2] * wc;
      ts1[r * LDP + j] = f2bf(fmaxf(a, 0.f));
    }
  }
  __syncthreads();
  int wave = tid >> 6, lane = tid & 63;
  int l15 = lane & 15, quad = lane >> 4;
  int rbase = (wave >> 1) * 64, nbase = (wave & 1) * 64;
  f32x4 acc[4][4];
#pragma unroll
  for (int i = 0; i < 4; ++i)
#pragma unroll
    for (int j = 0; j < 4; ++j) acc[i][j] = (f32x4){0.f, 0.f, 0.f, 0.f};
  for (int kc = 0; kc < 4; ++kc) {
    int k0 = kc * 32 + quad * 8;
    s16x8 af[4], bf[4];
#pragma unroll
    for (int t = 0; t < 4; ++t)
      af[t] = *(const s16x8*)&ts1[(rbase + t * 16 + l15) * LDP + k0];
#pragma unroll
    for (int t = 0; t < 4; ++t)
      bf[t] = *(const s16x8*)&w2t[(size_t)(nbase + t * 16 + l15) * HID + k0];
#pragma unroll
    for (int i = 0; i < 4; ++i)
#pragma unroll
      for (int j = 0; j < 4; ++j)
        acc[i][j] = __builtin_amdgcn_mfma_f32_16x16x32_bf16(af[i], bf[j], acc[i][j], 0, 0, 0);
  }
  float ebv[4];
#pragma unroll
  for (int t = 0; t < 4; ++t) ebv[t] = eb2[nbase + t * 16 + l15];
#pragma unroll
  for (int tr = 0; tr < 4; ++tr)
#pragma unroll
    for (int reg = 0; reg < 4; ++reg) {
      int row = rbase + tr * 16 + quad * 4 + reg;   // C/D: col=lane&15, row=quad*4+reg
#pragma unroll
      for (int tc = 0; tc < 4; ++tc) {
        int col = nbase + tc * 16 + l15;
        e16[(size_t)(e0 + row) * HID + col] = f2bf(acc[tr][tc][reg] + ebv[tc]);
      }
    }
}

// ---------------- fused CSR-aggregate + conv MLP, 32-node tile ----------------
// phase A v4 (16B/lane): wave walks its nodes' edges in NODE-ALIGNED groups of 4.
//   quad q owns edge gb+q; lane covers 8 cols via uint4 (1 KB/wave-instr for e
//   and for h). Per-quad fp32 partials accumulate across the node's groups;
//   at node end: 2-step shfl_xor butterfly across quads + one b128 RMW into zs
//   by quad 0. src 3-deep / e,h 2-deep pipeline. zs pre-init = h (degree-0 ok).
__global__ void __launch_bounds__(256) k_conv_csr(
    const unsigned short* __restrict__ h16in, const unsigned short* __restrict__ e16,
    const int* __restrict__ src_s, const int* __restrict__ rowptr,
    const unsigned short* __restrict__ w1t, const float* __restrict__ b1,
    const unsigned short* __restrict__ w2t, const float* __restrict__ b2,
    unsigned short* __restrict__ h16out, int nN) {
  __shared__ __attribute__((aligned(16))) unsigned short zs[32 * LDP];
  __shared__ int rpS[4][12];
  int tid = threadIdx.x;
  int n0 = blockIdx.x * 32;
  int wave = tid >> 6, lane = tid & 63;
  int l15 = lane & 15, quad = lane >> 4;
  // phase A
  {
    int c16 = l15 * 8;                  // halfword col base (16 B chunk)
    int c2 = lane * 2;
    int wbase = wave * 8;
    int nodeBase = n0 + wbase;
    int nCnt = nN - nodeBase; if (nCnt > 8) nCnt = 8; if (nCnt < 0) nCnt = 0;
#pragma unroll
    for (int i = 0; i < 8; ++i) {
      int n = nodeBase + i;
      unsigned int hv = 0u;
      if (n < nN) hv = *(const unsigned int*)&h16in[(size_t)n * HID + c2];
      *(unsigned int*)&zs[(wbase + i) * LDP + c2] = hv;
    }
    if (lane < 9) {
      int i = (lane < nCnt) ? lane : nCnt;
      rpS[wave][lane] = (nCnt > 0) ? rowptr[nodeBase + i] : 0;
    }
    if (nCnt > 0) {
      int gb = rpS[wave][0];
      int gEnd = rpS[wave][8];
      int ni = 0;
      while (ni < 8 && rpS[wave][ni + 1] <= gb) ++ni;
      int re = (ni < 8) ? rpS[wave][ni + 1] : gb;
      float acc[8];
#pragma unroll
      for (int j = 0; j < 8; ++j) acc[j] = 0.f;

      int eixA = 0, eixB = 0, eixC = 0, svA = 0, svB = 0, svC = 0;
      int niA = 0, niB = 0, niC = 0;
      bool vA = false, vB = false, vC = false, lA = false, lB = false, lC = false;
      uint4 evA, hvA, evB, hvB;
      bool aA = false, aB = false, aC = false;

#define PS(eix, sv, v, l, nis)                                   \
  { int gq = gb + quad;                                          \
    eix = (gq < re) ? gq : (re - 1);                             \
    v = (gq < re);                                               \
    l = (gb + 4 >= re);                                          \
    nis = ni;                                                    \
    sv = src_s[eix];                                             \
    gb = (gb + 4 < re) ? (gb + 4) : re;                          \
    if (gb >= re) {                                              \
      while (ni < 8 && rpS[wave][ni + 1] <= gb) ++ni;            \
      if (ni < 8) re = rpS[wave][ni + 1];                        \
    } }
#define PEH(ev, hv, eix, sv)                                     \
  { ev = *(const uint4*)&e16[(size_t)eix * HID + c16];           \
    hv = *(const uint4*)&h16in[(size_t)sv * HID + c16]; }
#define FOLDX(ev, hv, v, l, nis)                                 \
  { const unsigned int* ew = (const unsigned int*)&ev;           \
    const unsigned int* hw = (const unsigned int*)&hv;           \
    if (v) {                                                     \
      _Pragma("unroll")                                          \
      for (int j = 0; j < 4; ++j) {                              \
        acc[2*j]   += fmaxf(asf(hw[j] << 16) + asf(ew[j] << 16), 0.f); \
        acc[2*j+1] += fmaxf(asf(hw[j] & 0xffff0000u) + asf(ew[j] & 0xffff0000u), 0.f); \
      }                                                          \
    }                                                            \
    if (l) {                                                     \
      _Pragma("unroll")                                          \
      for (int j = 0; j < 8; ++j) {                              \
        acc[j] += __shfl_xor(acc[j], 16);                        \
        acc[j] += __shfl_xor(acc[j], 32);                        \
      }                                                          \
      if (quad == 0) {                                           \
        int row = wbase + nis;                                   \
        uint4 z = *(const uint4*)&zs[row * LDP + c16];           \
        unsigned int* zw = (unsigned int*)&z;                    \
        _Pragma("unroll")                                        \
        for (int j = 0; j < 4; ++j) {                            \
          float z0 = asf(zw[j] << 16) + acc[2*j];                \
          float z1 = asf(zw[j] & 0xffff0000u) + acc[2*j+1];      \
          zw[j] = (unsigned int)f2bf(z0) | ((unsigned int)f2bf(z1) << 16); \
        }                                                        \
        *(uint4*)&zs[row * LDP + c16] = z;                       \
      }                                                          \
      _Pragma("unroll")                                          \
      for (int j = 0; j < 8; ++j) acc[j] = 0.f;                  \
    } }

      if (gb < gEnd) { PS(eixA, svA, vA, lA, niA) aA = true; }
      if (gb < gEnd) { PS(eixB, svB, vB, lB, niB) aB = true; }
      if (aA) PEH(evA, hvA, eixA, svA)
      while (aA) {
        aC = (gb < gEnd);
        if (aC) PS(eixC, svC, vC, lC, niC)
        if (aB) PEH(evB, hvB, eixB, svB)
        FOLDX(evA, hvA, vA, lA, niA)
        aA = aB; evA = evB; hvA = hvB; vA = vB; lA = lB; niA = niB; eixA = eixB; svA = svB;
        aB = aC; eixB = eixC; svB = svC; vB = vC; lB = lC; niB = niC;
      }
#undef PS
#undef PEH
#undef FOLDX
    }
  }
  __syncthreads();
  int rbase = (wave >> 1) * 16, nbase = (wave & 1) * 64;
  f32x4 acc[4];
#pragma unroll
  for (int j = 0; j < 4; ++j) acc[j] = (f32x4){0.f, 0.f, 0.f, 0.f};
  for (int kc = 0; kc < 4; ++kc) {
    int k0 = kc * 32 + quad * 8;
    s16x8 af, bf[4];
    af = *(const s16x8*)&zs[(rbase + l15) * LDP + k0];
#pragma unroll
    for (int t = 0; t < 4; ++t)
      bf[t] = *(const s16x8*)&w1t[(size_t)(nbase + t * 16 + l15) * HID + k0];
#pragma unroll
    for (int j = 0; j < 4; ++j)
      acc[j] = __builtin_amdgcn_mfma_f32_16x16x32_bf16(af, bf[j], acc[j], 0, 0, 0);
  }
  __syncthreads();
  {
    float bv[4];
#pragma unroll
    for (int t = 0; t < 4; ++t) bv[t] = b1[nbase + t * 16 + l15];
#pragma unroll
    for (int tc = 0; tc < 4; ++tc)
#pragma unroll
      for (int reg = 0; reg < 4; ++reg) {
        int row = rbase + quad * 4 + reg;
        int col = nbase + tc * 16 + l15;
        zs[row * LDP + col] = f2bf(fmaxf(acc[tc][reg] + bv[tc], 0.f));
      }
  }
  __syncthreads();
#pragma unroll
  for (int j = 0; j < 4; ++j) acc[j] = (f32x4){0.f, 0.f, 0.f, 0.f};
  for (int kc = 0; kc < 4; ++kc) {
    int k0 = kc * 32 + quad * 8;
    s16x8 af, bf[4];
    af = *(const s16x8*)&zs[(rbase + l15) * LDP + k0];
#pragma unroll
    for (int t = 0; t < 4; ++t)
      bf[t] = *(const s16x8*)&w2t[(size_t)(nbase + t * 16 + l15) * HID + k0];
#pragma unroll
    for (int j = 0; j < 4; ++j)
      acc[j] = __builtin_amdgcn_mfma_f32_16x16x32_bf16(af, bf[j], acc[j], 0, 0, 0);
  }
  {
    float bv[4];
#pragma unroll
    for (int t = 0; t < 4; ++t) bv[t] = b2[nbase + t * 16 + l15];
#pragma unroll
    for (int reg = 0; reg < 4; ++reg) {
      int grow = n0 + rbase + quad * 4 + reg;
      if (grow < nN) {
#pragma unroll
        for (int tc = 0; tc < 4; ++tc) {
          int col = nbase + tc * 16 + l15;
          h16out[(size_t)grow * HID + col] = f2bf(fmaxf(acc[tc][reg] + bv[tc], 0.f));
        }
      }
    }
  }
}

// ---------------- counts ----------------
__global__ void k_counts(const int* __restrict__ batch, int* __restrict__ cnts, int nN) {
  int i = blockIdx.x * blockDim.x + threadIdx.x;
  if (i < nN) atomicAdd(&cnts[batch[i]], 1);
}

// ---------------- segment-reduced pool (batch sorted) ----------------
__global__ void __launch_bounds__(256) k_pool2(
    const unsigned short* __restrict__ h16, const int* __restrict__ batch,
    float* __restrict__ g, int nN) {
  __shared__ int bL[128];
  int tid = threadIdx.x;
  int n0 = blockIdx.x * 128;
  if (tid < 128) {
    int n = n0 + tid;
    bL[tid] = (n < nN) ? batch[n] : -1;
  }
  __syncthreads();
  int half = tid >> 7, col = tid & 127;
  int rs = half * 64;
  int cur = -1;
  float s = 0.f;
  for (int r = rs; r < rs + 64; ++r) {
    int b = bL[r];
    float v = (b >= 0) ? bf2f((unsigned int)h16[(size_t)(n0 + r) * HID + col]) : 0.f;
    if (b != cur) {
      if (cur >= 0) atomicAdd(&g[(size_t)cur * HID + col], s);
      cur = b; s = v;
    } else s += v;
  }
  if (cur >= 0) atomicAdd(&g[(size_t)cur * HID + col], s);
}

// ---------------- heads ----------------
__global__ void __launch_bounds__(128) k_head(
    const float* __restrict__ g, const int* __restrict__ counts,
    const float* __restrict__ clw1, const float* __restrict__ clb1,
    const float* __restrict__ clw2, const float* __restrict__ clb2,
    const float* __restrict__ rw1, const float* __restrict__ rb1,
    const float* __restrict__ rw2, const float* __restrict__ rb2,
    float* __restrict__ out, int nG) {
  __shared__ float gs[HID];
  int b = blockIdx.x;
  int tid = threadIdx.x;
  float cnt = fmaxf((float)counts[b], 1.f);
  gs[tid] = g[b * HID + tid] / cnt;
  __syncthreads();
  int wave = tid >> 6, lane = tid & 63;
  const float* w1 = wave ? rw1 : clw1;
  const float* b1 = wave ? rb1 : clb1;
  const float* w2 = wave ? rw2 : clw2;
  const float* b2 = wave ? rb2 : clb2;
  float acc = b1[lane];
  for (int k = 0; k < HID; ++k) acc += gs[k] * w1[k * 64 + lane];
  acc = fmaxf(acc, 0.f) * w2[lane];
#pragma unroll
  for (int off = 32; off; off >>= 1) acc += __shfl_down(acc, off);
  if (lane == 0) out[wave * nG + b] = acc + b2[0];
}

extern "C" void kernel_launch(void* const* d_in, const int* in_sizes, int n_in,
                              void* d_out, int out_size, void* d_ws, size_t ws_size,
                              hipStream_t stream) {
  const float* x      = (const float*)d_in[0];
  const float* ea     = (const float*)d_in[1];
  const int*   eidx   = (const int*)d_in[2];
  const int*   batch  = (const int*)d_in[3];
  const float* node_w = (const float*)d_in[4];
  const float* node_b = (const float*)d_in[5];
  const float* ew1    = (const float*)d_in[6];
  const float* eb1    = (const float*)d_in[7];
  const float* ew2    = (const float*)d_in[8];
  const float* eb2    = (const float*)d_in[9];
  const float* cw1    = (const float*)d_in[10];
  const float* cb1    = (const float*)d_in[11];
  const float* cw2    = (const float*)d_in[12];
  const float* cb2    = (const float*)d_in[13];
  const float* clw1   = (const float*)d_in[14];
  const float* clb1   = (const float*)d_in[15];
  const float* clw2   = (const float*)d_in[16];
  const float* clb2   = (const float*)d_in[17];
  const float* rw1    = (const float*)d_in[18];
  const float* rb1    = (const float*)d_in[19];
  const float* rw2    = (const float*)d_in[20];
  const float* rb2    = (const float*)d_in[21];
  float* out = (float*)d_out;

  int nN = in_sizes[3];        // 100000
  int nE = in_sizes[2] / 2;    // 640000 (divisible by 128)
  int nG = out_size / 2;       // 2048
  const int* src = eidx;
  const int* dst = eidx + nE;

  int NB = (nN + 255) / 256;
  int bins = NB * 256;

  // ---- workspace (~231 MB) ----
  size_t hN = (size_t)nN * HID;
  size_t gN = (size_t)nG * HID;
  float* g    = (float*)d_ws;                       // gN
  int*   cnts = (int*)(g + gN);                     // nG
  unsigned short* wT   = (unsigned short*)(cnts + nG);  // 7*16384
  unsigned short* h16a = wT + 7 * 16384;            // hN
  unsigned short* h16b = h16a + hN;                 // hN
  int* deg    = (int*)(h16b + hN);                  // bins
  int* cursor = deg + bins;                         // bins
  int* rowptr = cursor + bins;                      // bins
  int* bsum   = rowptr + bins;                      // 512
  int* bsumx  = bsum + 512;                         // 512
  int* src_s  = bsumx + 512;                        // nE
  float* ea_s = (float*)(src_s + nE);               // 3*nE
  unsigned short* e16 = (unsigned short*)(ea_s + (size_t)3 * nE);  // nE*128

  // ---- counting sort of edges by dst (also builds CSR rowptr) ----
  k_zero4<<<(int)((bins / 4 + 255) / 256), 256, 0, stream>>>((float4*)deg, bins / 4);
  k_hist<<<(nE + 255) / 256, 256, 0, stream>>>(dst, deg, nE);
  k_scanA<<<NB, 256, 0, stream>>>(deg, bsum);
  k_scanB<<<1, 512, 0, stream>>>(bsum, bsumx, NB);
  k_scanC<<<NB, 256, 0, stream>>>(deg, bsumx, cursor, rowptr);
  k_scatter<<<(nE + 255) / 256, 256, 0, stream>>>(src, dst, ea, cursor, src_s, ea_s, nE);

  k_prep_w<<<(7 * 16384 + 255) / 256, 256, 0, stream>>>(ew2, cw1, cw2, wT);
  k_edge_gemm<<<nE / 128, 256, 0, stream>>>(ea_s, ew1, eb1, wT, eb2, e16, nE);
  k_node_enc<<<(nN * HID + 255) / 256, 256, 0, stream>>>(x, node_w, node_b, h16a, nN);

  // ping-pong: A->B, B->A, A->B  (final in h16b)
  unsigned short* hin  = h16a;
  unsigned short* hout = h16b;
  for (int l = 0; l < 3; ++l) {
    k_conv_csr<<<(nN + 31) / 32, 256, 0, stream>>>(
        hin, e16, src_s, rowptr,
        wT + (size_t)(1 + l) * 16384, cb1 + (size_t)l * HID,
        wT + (size_t)(4 + l) * 16384, cb2 + (size_t)l * HID, hout, nN);
    unsigned short* t = hin; hin = hout; hout = t;
  }

  k_zero4<<<(int)(((gN + nG) / 4 + 255) / 256), 256, 0, stream>>>((float4*)g, (gN + nG) / 4);
  k_counts<<<(nN + 255) / 256, 256, 0, stream>>>(batch, cnts, nN);
  k_pool2<<<(nN + 127) / 128, 256, 0, stream>>>(hin, batch, g, nN);
  k_head<<<nG, 128, 0, stream>>>(g, cnts, clw1, clb1, clw2, clb2,
                                 rw1, rb1, rw2, rb2, out, nG);
}

// Round 17
// 606.978 us; speedup vs baseline: 1.1252x; 1.0396x over previous
//
#include <hip/hip_runtime.h>

#define HID 128
#define LDP 136   // padded LDS row stride in bf16 elems (272 B)

typedef short s16x8 __attribute__((ext_vector_type(8)));
typedef float f32x4 __attribute__((ext_vector_type(4)));
typedef float f32x2 __attribute__((ext_vector_type(2)));

__device__ __forceinline__ float bf2f(unsigned int u) {
  union { unsigned int i; float f; } v; v.i = u << 16; return v.f;
}
__device__ __forceinline__ float asf(unsigned int u) {
  union { unsigned int i; float f; } v; v.i = u; return v.f;
}
__device__ __forceinline__ unsigned short f2bf(float f) {
  union { float f; unsigned int i; } v; v.f = f;
  unsigned int r = v.i + 0x7fffu + ((v.i >> 16) & 1u);
  return (unsigned short)(r >> 16);
}
// f32 -> fp8 e4m3 byte (RNE, via HW cvt)
__device__ __forceinline__ unsigned char f2fp8(float f) {
  unsigned int p = __builtin_amdgcn_cvt_pk_fp8_f32(f, f, 0u, false);
  return (unsigned char)(p & 0xffu);
}

// ---------------- zero fill (vectorized) ----------------
__global__ void k_zero4(float4* __restrict__ p, size_t n4) {
  size_t i = (size_t)blockIdx.x * blockDim.x + threadIdx.x;
  if (i < n4) p[i] = (float4){0.f, 0.f, 0.f, 0.f};
}

// ---------------- counting sort ----------------
__global__ void k_hist(const int* __restrict__ dst, int* __restrict__ deg, int nE) {
  int e = blockIdx.x * blockDim.x + threadIdx.x;
  if (e < nE) atomicAdd(&deg[dst[e]], 1);
}

__global__ void k_scanA(const int* __restrict__ deg, int* __restrict__ bsum) {
  __shared__ int ss[256];
  int t = threadIdx.x;
  ss[t] = deg[blockIdx.x * 256 + t];
  __syncthreads();
  for (int off = 128; off; off >>= 1) {
    if (t < off) ss[t] += ss[t + off];
    __syncthreads();
  }
  if (t == 0) bsum[blockIdx.x] = ss[0];
}

__global__ void k_scanB(const int* __restrict__ bsum, int* __restrict__ bsumx, int NB) {
  __shared__ int sd[512];
  int t = threadIdx.x;
  int v = (t < NB) ? bsum[t] : 0;
  sd[t] = v;
  __syncthreads();
  for (int off = 1; off < 512; off <<= 1) {
    int a = (t >= off) ? sd[t - off] : 0;
    __syncthreads();
    sd[t] += a;
    __syncthreads();
  }
  if (t < NB) bsumx[t] = sd[t] - v;
}

// exclusive scan to BOTH cursor (mutated by scatter) and rowptr (kept)
__global__ void k_scanC(const int* __restrict__ deg, const int* __restrict__ bsumx,
                        int* __restrict__ cursor, int* __restrict__ rowptr) {
  __shared__ int ss[256];
  int t = threadIdx.x, i = blockIdx.x * 256 + t;
  int v = deg[i];
  ss[t] = v;
  __syncthreads();
  for (int off = 1; off < 256; off <<= 1) {
    int a = (t >= off) ? ss[t - off] : 0;
    __syncthreads();
    ss[t] += a;
    __syncthreads();
  }
  int ex = ss[t] - v + bsumx[blockIdx.x];
  cursor[i] = ex;
  rowptr[i] = ex;
}

__global__ void k_scatter(const int* __restrict__ src, const int* __restrict__ dst,
                          const float* __restrict__ ea, int* __restrict__ cursor,
                          int* __restrict__ src_s, float* __restrict__ ea_s, int nE) {
  int e = blockIdx.x * blockDim.x + threadIdx.x;
  if (e >= nE) return;
  int d = dst[e];
  int pos = atomicAdd(&cursor[d], 1);
  src_s[pos] = src[e];
  ea_s[(size_t)pos * 3 + 0] = ea[(size_t)e * 3 + 0];
  ea_s[(size_t)pos * 3 + 1] = ea[(size_t)e * 3 + 1];
  ea_s[(size_t)pos * 3 + 2] = ea[(size_t)e * 3 + 2];
}

// ---------------- transpose weights to bf16 ----------------
__global__ void k_prep_w(const float* __restrict__ ew2, const float* __restrict__ cw1,
                         const float* __restrict__ cw2, unsigned short* __restrict__ wT) {
  int idx = blockIdx.x * blockDim.x + threadIdx.x;
  if (idx >= 7 * 16384) return;
  int m = idx >> 14, i = idx & 16383;
  int n = i >> 7, k = i & 127;
  const float* s = (m == 0) ? ew2 : (m <= 3 ? cw1 + (size_t)(m - 1) * 16384
                                            : cw2 + (size_t)(m - 4) * 16384);
  wT[idx] = f2bf(s[k * 128 + n]);
}

// ---------------- node encoder ----------------
__global__ void k_node_enc(const float* __restrict__ x, const float* __restrict__ w,
                           const float* __restrict__ b, unsigned short* __restrict__ h16, int nN) {
  int idx = blockIdx.x * blockDim.x + threadIdx.x;
  if (idx >= nN * HID) return;
  int i = idx >> 7, j = idx & 127;
  float acc = b[j];
  const float* xr = x + (size_t)i * 7;
#pragma unroll
  for (int k = 0; k < 7; ++k) acc += xr[k] * w[k * HID + j];
  h16[idx] = f2bf(acc);
}

// ---------------- one-time edge encoder GEMM -> e8 (fp8 e4m3, direct C/D stores) ----------------
__global__ void __launch_bounds__(256) k_edge_gemm(
    const float* __restrict__ ea_s, const float* __restrict__ ew1, const float* __restrict__ eb1,
    const unsigned short* __restrict__ w2t, const float* __restrict__ eb2,
    unsigned char* __restrict__ e8, int nE) {
  __shared__ __attribute__((aligned(16))) unsigned short ts1[128 * LDP];
  __shared__ float eaL[384];
  int tid = threadIdx.x;
  int e0 = blockIdx.x * 128;                      // nE % 128 == 0
  for (int i = tid; i < 384; i += 256) eaL[i] = ea_s[(size_t)e0 * 3 + i];
  __syncthreads();
  {
    int j = tid & 127, r0 = (tid >> 7) * 64;
    float wa = ew1[j], wb = ew1[HID + j], wc = ew1[2 * HID + j], bj = eb1[j];
    for (int r = r0; r < r0 + 64; ++r) {
      float a = bj + eaL[r * 3] * wa + eaL[r * 3 + 1] * wb + eaL[r * 3 + 2] * wc;
      ts1[r * LDP + j] = f2bf(fmaxf(a, 0.f));
    }
  }
  __syncthreads();
  int wave = tid >> 6, lane = tid & 63;
  int l15 = lane & 15, quad = lane >> 4;
  int rbase = (wave >> 1) * 64, nbase = (wave & 1) * 64;
  f32x4 acc[4][4];
#pragma unroll
  for (int i = 0; i < 4; ++i)
#pragma unroll
    for (int j = 0; j < 4; ++j) acc[i][j] = (f32x4){0.f, 0.f, 0.f, 0.f};
  for (int kc = 0; kc < 4; ++kc) {
    int k0 = kc * 32 + quad * 8;
    s16x8 af[4], bf[4];
#pragma unroll
    for (int t = 0; t < 4; ++t)
      af[t] = *(const s16x8*)&ts1[(rbase + t * 16 + l15) * LDP + k0];
#pragma unroll
    for (int t = 0; t < 4; ++t)
      bf[t] = *(const s16x8*)&w2t[(size_t)(nbase + t * 16 + l15) * HID + k0];
#pragma unroll
    for (int i = 0; i < 4; ++i)
#pragma unroll
      for (int j = 0; j < 4; ++j)
        acc[i][j] = __builtin_amdgcn_mfma_f32_16x16x32_bf16(af[i], bf[j], acc[i][j], 0, 0, 0);
  }
  float ebv[4];
#pragma unroll
  for (int t = 0; t < 4; ++t) ebv[t] = eb2[nbase + t * 16 + l15];
#pragma unroll
  for (int tr = 0; tr < 4; ++tr)
#pragma unroll
    for (int reg = 0; reg < 4; ++reg) {
      int row = rbase + tr * 16 + quad * 4 + reg;   // C/D: col=lane&15, row=quad*4+reg
#pragma unroll
      for (int tc = 0; tc < 4; ++tc) {
        int col = nbase + tc * 16 + l15;
        e8[(size_t)(e0 + row) * HID + col] = f2fp8(acc[tr][tc][reg] + ebv[tc]);
      }
    }
}

// ---------------- fused CSR-aggregate + conv MLP, 32-node tile ----------------
// phase A (16B/lane, fp8 e): node-aligned groups of 4 edges; quad q owns edge
//   gb+q; lane covers 8 cols: e via uint2 (8 B fp8), h via uint4 (16 B bf16).
//   fp32 per-quad partials; node-end: shfl_xor butterfly + quad-0 b128 RMW.
__global__ void __launch_bounds__(256) k_conv_csr(
    const unsigned short* __restrict__ h16in, const unsigned char* __restrict__ e8,
    const int* __restrict__ src_s, const int* __restrict__ rowptr,
    const unsigned short* __restrict__ w1t, const float* __restrict__ b1,
    const unsigned short* __restrict__ w2t, const float* __restrict__ b2,
    unsigned short* __restrict__ h16out, int nN) {
  __shared__ __attribute__((aligned(16))) unsigned short zs[32 * LDP];
  __shared__ int rpS[4][12];
  int tid = threadIdx.x;
  int n0 = blockIdx.x * 32;
  int wave = tid >> 6, lane = tid & 63;
  int l15 = lane & 15, quad = lane >> 4;
  // phase A
  {
    int c16 = l15 * 8;                  // col base (8 cols per lane)
    int c2 = lane * 2;
    int wbase = wave * 8;
    int nodeBase = n0 + wbase;
    int nCnt = nN - nodeBase; if (nCnt > 8) nCnt = 8; if (nCnt < 0) nCnt = 0;
#pragma unroll
    for (int i = 0; i < 8; ++i) {
      int n = nodeBase + i;
      unsigned int hv = 0u;
      if (n < nN) hv = *(const unsigned int*)&h16in[(size_t)n * HID + c2];
      *(unsigned int*)&zs[(wbase + i) * LDP + c2] = hv;
    }
    if (lane < 9) {
      int i = (lane < nCnt) ? lane : nCnt;
      rpS[wave][lane] = (nCnt > 0) ? rowptr[nodeBase + i] : 0;
    }
    if (nCnt > 0) {
      int gb = rpS[wave][0];
      int gEnd = rpS[wave][8];
      int ni = 0;
      while (ni < 8 && rpS[wave][ni + 1] <= gb) ++ni;
      int re = (ni < 8) ? rpS[wave][ni + 1] : gb;
      float acc[8];
#pragma unroll
      for (int j = 0; j < 8; ++j) acc[j] = 0.f;

      int eixA = 0, eixB = 0, eixC = 0, svA = 0, svB = 0, svC = 0;
      int niA = 0, niB = 0, niC = 0;
      bool vA = false, vB = false, vC = false, lA = false, lB = false, lC = false;
      uint2 evA, evB;
      uint4 hvA, hvB;
      bool aA = false, aB = false, aC = false;

#define PS(eix, sv, v, l, nis)                                   \
  { int gq = gb + quad;                                          \
    eix = (gq < re) ? gq : (re - 1);                             \
    v = (gq < re);                                               \
    l = (gb + 4 >= re);                                          \
    nis = ni;                                                    \
    sv = src_s[eix];                                             \
    gb = (gb + 4 < re) ? (gb + 4) : re;                          \
    if (gb >= re) {                                              \
      while (ni < 8 && rpS[wave][ni + 1] <= gb) ++ni;            \
      if (ni < 8) re = rpS[wave][ni + 1];                        \
    } }
#define PEH(ev, hv, eix, sv)                                     \
  { ev = *(const uint2*)&e8[(size_t)eix * HID + c16];            \
    hv = *(const uint4*)&h16in[(size_t)sv * HID + c16]; }
#define FOLDX(ev, hv, v, l, nis)                                 \
  { const unsigned int* ew = (const unsigned int*)&ev;           \
    const unsigned int* hw = (const unsigned int*)&hv;           \
    if (v) {                                                     \
      _Pragma("unroll")                                          \
      for (int j = 0; j < 2; ++j) {                              \
        f32x2 pa = __builtin_amdgcn_cvt_pk_f32_fp8(ew[j], false); \
        f32x2 pb = __builtin_amdgcn_cvt_pk_f32_fp8(ew[j], true);  \
        acc[4*j+0] += fmaxf(asf(hw[2*j] << 16) + pa[0], 0.f);    \
        acc[4*j+1] += fmaxf(asf(hw[2*j] & 0xffff0000u) + pa[1], 0.f); \
        acc[4*j+2] += fmaxf(asf(hw[2*j+1] << 16) + pb[0], 0.f);  \
        acc[4*j+3] += fmaxf(asf(hw[2*j+1] & 0xffff0000u) + pb[1], 0.f); \
      }                                                          \
    }                                                            \
    if (l) {                                                     \
      _Pragma("unroll")                                          \
      for (int j = 0; j < 8; ++j) {                              \
        acc[j] += __shfl_xor(acc[j], 16);                        \
        acc[j] += __shfl_xor(acc[j], 32);                        \
      }                                                          \
      if (quad == 0) {                                           \
        int row = wbase + nis;                                   \
        uint4 z = *(const uint4*)&zs[row * LDP + c16];           \
        unsigned int* zw = (unsigned int*)&z;                    \
        _Pragma("unroll")                                        \
        for (int j = 0; j < 4; ++j) {                            \
          float z0 = asf(zw[j] << 16) + acc[2*j];                \
          float z1 = asf(zw[j] & 0xffff0000u) + acc[2*j+1];      \
          zw[j] = (unsigned int)f2bf(z0) | ((unsigned int)f2bf(z1) << 16); \
        }                                                        \
        *(uint4*)&zs[row * LDP + c16] = z;                       \
      }                                                          \
      _Pragma("unroll")                                          \
      for (int j = 0; j < 8; ++j) acc[j] = 0.f;                  \
    } }

      if (gb < gEnd) { PS(eixA, svA, vA, lA, niA) aA = true; }
      if (gb < gEnd) { PS(eixB, svB, vB, lB, niB) aB = true; }
      if (aA) PEH(evA, hvA, eixA, svA)
      while (aA) {
        aC = (gb < gEnd);
        if (aC) PS(eixC, svC, vC, lC, niC)
        if (aB) PEH(evB, hvB, eixB, svB)
        FOLDX(evA, hvA, vA, lA, niA)
        aA = aB; evA = evB; hvA = hvB; vA = vB; lA = lB; niA = niB; eixA = eixB; svA = svB;
        aB = aC; eixB = eixC; svB = svC; vB = vC; lB = lC; niB = niC;
      }
#undef PS
#undef PEH
#undef FOLDX
    }
  }
  __syncthreads();
  int rbase = (wave >> 1) * 16, nbase = (wave & 1) * 64;
  f32x4 acc[4];
#pragma unroll
  for (int j = 0; j < 4; ++j) acc[j] = (f32x4){0.f, 0.f, 0.f, 0.f};
  for (int kc = 0; kc < 4; ++kc) {
    int k0 = kc * 32 + quad * 8;
    s16x8 af, bf[4];
    af = *(const s16x8*)&zs[(rbase + l15) * LDP + k0];
#pragma unroll
    for (int t = 0; t < 4; ++t)
      bf[t] = *(const s16x8*)&w1t[(size_t)(nbase + t * 16 + l15) * HID + k0];
#pragma unroll
    for (int j = 0; j < 4; ++j)
      acc[j] = __builtin_amdgcn_mfma_f32_16x16x32_bf16(af, bf[j], acc[j], 0, 0, 0);
  }
  __syncthreads();
  {
    float bv[4];
#pragma unroll
    for (int t = 0; t < 4; ++t) bv[t] = b1[nbase + t * 16 + l15];
#pragma unroll
    for (int tc = 0; tc < 4; ++tc)
#pragma unroll
      for (int reg = 0; reg < 4; ++reg) {
        int row = rbase + quad * 4 + reg;
        int col = nbase + tc * 16 + l15;
        zs[row * LDP + col] = f2bf(fmaxf(acc[tc][reg] + bv[tc], 0.f));
      }
  }
  __syncthreads();
#pragma unroll
  for (int j = 0; j < 4; ++j) acc[j] = (f32x4){0.f, 0.f, 0.f, 0.f};
  for (int kc = 0; kc < 4; ++kc) {
    int k0 = kc * 32 + quad * 8;
    s16x8 af, bf[4];
    af = *(const s16x8*)&zs[(rbase + l15) * LDP + k0];
#pragma unroll
    for (int t = 0; t < 4; ++t)
      bf[t] = *(const s16x8*)&w2t[(size_t)(nbase + t * 16 + l15) * HID + k0];
#pragma unroll
    for (int j = 0; j < 4; ++j)
      acc[j] = __builtin_amdgcn_mfma_f32_16x16x32_bf16(af, bf[j], acc[j], 0, 0, 0);
  }
  {
    float bv[4];
#pragma unroll
    for (int t = 0; t < 4; ++t) bv[t] = b2[nbase + t * 16 + l15];
#pragma unroll
    for (int reg = 0; reg < 4; ++reg) {
      int grow = n0 + rbase + quad * 4 + reg;
      if (grow < nN) {
#pragma unroll
        for (int tc = 0; tc < 4; ++tc) {
          int col = nbase + tc * 16 + l15;
          h16out[(size_t)grow * HID + col] = f2bf(fmaxf(acc[tc][reg] + bv[tc], 0.f));
        }
      }
    }
  }
}

// ---------------- counts ----------------
__global__ void k_counts(const int* __restrict__ batch, int* __restrict__ cnts, int nN) {
  int i = blockIdx.x * blockDim.x + threadIdx.x;
  if (i < nN) atomicAdd(&cnts[batch[i]], 1);
}

// ---------------- segment-reduced pool (batch sorted) ----------------
__global__ void __launch_bounds__(256) k_pool2(
    const unsigned short* __restrict__ h16, const int* __restrict__ batch,
    float* __restrict__ g, int nN) {
  __shared__ int bL[128];
  int tid = threadIdx.x;
  int n0 = blockIdx.x * 128;
  if (tid < 128) {
    int n = n0 + tid;
    bL[tid] = (n < nN) ? batch[n] : -1;
  }
  __syncthreads();
  int half = tid >> 7, col = tid & 127;
  int rs = half * 64;
  int cur = -1;
  float s = 0.f;
  for (int r = rs; r < rs + 64; ++r) {
    int b = bL[r];
    float v = (b >= 0) ? bf2f((unsigned int)h16[(size_t)(n0 + r) * HID + col]) : 0.f;
    if (b != cur) {
      if (cur >= 0) atomicAdd(&g[(size_t)cur * HID + col], s);
      cur = b; s = v;
    } else s += v;
  }
  if (cur >= 0) atomicAdd(&g[(size_t)cur * HID + col], s);
}

// ---------------- heads ----------------
__global__ void __launch_bounds__(128) k_head(
    const float* __restrict__ g, const int* __restrict__ counts,
    const float* __restrict__ clw1, const float* __restrict__ clb1,
    const float* __restrict__ clw2, const float* __restrict__ clb2,
    const float* __restrict__ rw1, const float* __restrict__ rb1,
    const float* __restrict__ rw2, const float* __restrict__ rb2,
    float* __restrict__ out, int nG) {
  __shared__ float gs[HID];
  int b = blockIdx.x;
  int tid = threadIdx.x;
  float cnt = fmaxf((float)counts[b], 1.f);
  gs[tid] = g[b * HID + tid] / cnt;
  __syncthreads();
  int wave = tid >> 6, lane = tid & 63;
  const float* w1 = wave ? rw1 : clw1;
  const float* b1 = wave ? rb1 : clb1;
  const float* w2 = wave ? rw2 : clw2;
  const float* b2 = wave ? rb2 : clb2;
  float acc = b1[lane];
  for (int k = 0; k < HID; ++k) acc += gs[k] * w1[k * 64 + lane];
  acc = fmaxf(acc, 0.f) * w2[lane];
#pragma unroll
  for (int off = 32; off; off >>= 1) acc += __shfl_down(acc, off);
  if (lane == 0) out[wave * nG + b] = acc + b2[0];
}

extern "C" void kernel_launch(void* const* d_in, const int* in_sizes, int n_in,
                              void* d_out, int out_size, void* d_ws, size_t ws_size,
                              hipStream_t stream) {
  const float* x      = (const float*)d_in[0];
  const float* ea     = (const float*)d_in[1];
  const int*   eidx   = (const int*)d_in[2];
  const int*   batch  = (const int*)d_in[3];
  const float* node_w = (const float*)d_in[4];
  const float* node_b = (const float*)d_in[5];
  const float* ew1    = (const float*)d_in[6];
  const float* eb1    = (const float*)d_in[7];
  const float* ew2    = (const float*)d_in[8];
  const float* eb2    = (const float*)d_in[9];
  const float* cw1    = (const float*)d_in[10];
  const float* cb1    = (const float*)d_in[11];
  const float* cw2    = (const float*)d_in[12];
  const float* cb2    = (const float*)d_in[13];
  const float* clw1   = (const float*)d_in[14];
  const float* clb1   = (const float*)d_in[15];
  const float* clw2   = (const float*)d_in[16];
  const float* clb2   = (const float*)d_in[17];
  const float* rw1    = (const float*)d_in[18];
  const float* rb1    = (const float*)d_in[19];
  const float* rw2    = (const float*)d_in[20];
  const float* rb2    = (const float*)d_in[21];
  float* out = (float*)d_out;

  int nN = in_sizes[3];        // 100000
  int nE = in_sizes[2] / 2;    // 640000 (divisible by 128)
  int nG = out_size / 2;       // 2048
  const int* src = eidx;
  const int* dst = eidx + nE;

  int NB = (nN + 255) / 256;
  int bins = NB * 256;

  // ---- workspace (~150 MB) ----
  size_t hN = (size_t)nN * HID;
  size_t gN = (size_t)nG * HID;
  float* g    = (float*)d_ws;                       // gN
  int*   cnts = (int*)(g + gN);                     // nG
  unsigned short* wT   = (unsigned short*)(cnts + nG);  // 7*16384
  unsigned short* h16a = wT + 7 * 16384;            // hN
  unsigned short* h16b = h16a + hN;                 // hN
  int* deg    = (int*)(h16b + hN);                  // bins
  int* cursor = deg + bins;                         // bins
  int* rowptr = cursor + bins;                      // bins
  int* bsum   = rowptr + bins;                      // 512
  int* bsumx  = bsum + 512;                         // 512
  int* src_s  = bsumx + 512;                        // nE
  float* ea_s = (float*)(src_s + nE);               // 3*nE
  unsigned char* e8 = (unsigned char*)(ea_s + (size_t)3 * nE);  // nE*128 fp8

  // ---- counting sort of edges by dst (also builds CSR rowptr) ----
  k_zero4<<<(int)((bins / 4 + 255) / 256), 256, 0, stream>>>((float4*)deg, bins / 4);
  k_hist<<<(nE + 255) / 256, 256, 0, stream>>>(dst, deg, nE);
  k_scanA<<<NB, 256, 0, stream>>>(deg, bsum);
  k_scanB<<<1, 512, 0, stream>>>(bsum, bsumx, NB);
  k_scanC<<<NB, 256, 0, stream>>>(deg, bsumx, cursor, rowptr);
  k_scatter<<<(nE + 255) / 256, 256, 0, stream>>>(src, dst, ea, cursor, src_s, ea_s, nE);

  k_prep_w<<<(7 * 16384 + 255) / 256, 256, 0, stream>>>(ew2, cw1, cw2, wT);
  k_edge_gemm<<<nE / 128, 256, 0, stream>>>(ea_s, ew1, eb1, wT, eb2, e8, nE);
  k_node_enc<<<(nN * HID + 255) / 256, 256, 0, stream>>>(x, node_w, node_b, h16a, nN);

  // ping-pong: A->B, B->A, A->B  (final in h16b)
  unsigned short* hin  = h16a;
  unsigned short* hout = h16b;
  for (int l = 0; l < 3; ++l) {
    k_conv_csr<<<(nN + 31) / 32, 256, 0, stream>>>(
        hin, e8, src_s, rowptr,
        wT + (size_t)(1 + l) * 16384, cb1 + (size_t)l * HID,
        wT + (size_t)(4 + l) * 16384, cb2 + (size_t)l * HID, hout, nN);
    unsigned short* t = hin; hin = hout; hout = t;
  }

  k_zero4<<<(int)(((gN + nG) / 4 + 255) / 256), 256, 0, stream>>>((float4*)g, (gN + nG) / 4);
  k_counts<<<(nN + 255) / 256, 256, 0, stream>>>(batch, cnts, nN);
  k_pool2<<<(nN + 127) / 128, 256, 0, stream>>>(hin, batch, g, nN);
  k_head<<<nG, 128, 0, stream>>>(g, cnts, clw1, clb1, clw2, clb2,
                                 rw1, rb1, rw2, rb2, out, nG);
}

// Round 18
// 605.172 us; speedup vs baseline: 1.1285x; 1.0030x over previous
//
#include <hip/hip_runtime.h>

#define HID 128
#define LDP 136   // padded LDS row stride in bf16 elems (272 B)

typedef short s16x8 __attribute__((ext_vector_type(8)));
typedef float f32x4 __attribute__((ext_vector_type(4)));
typedef float f32x2 __attribute__((ext_vector_type(2)));

__device__ __forceinline__ float bf2f(unsigned int u) {
  union { unsigned int i; float f; } v; v.i = u << 16; return v.f;
}
__device__ __forceinline__ float asf(unsigned int u) {
  union { unsigned int i; float f; } v; v.i = u; return v.f;
}
__device__ __forceinline__ unsigned short f2bf(float f) {
  union { float f; unsigned int i; } v; v.f = f;
  unsigned int r = v.i + 0x7fffu + ((v.i >> 16) & 1u);
  return (unsigned short)(r >> 16);
}
// f32 -> fp8 e4m3 byte (RNE, via HW cvt)
__device__ __forceinline__ unsigned char f2fp8(float f) {
  unsigned int p = __builtin_amdgcn_cvt_pk_fp8_f32(f, f, 0u, false);
  return (unsigned char)(p & 0xffu);
}

// ---------------- zero fill (vectorized) ----------------
__global__ void k_zero4(float4* __restrict__ p, size_t n4) {
  size_t i = (size_t)blockIdx.x * blockDim.x + threadIdx.x;
  if (i < n4) p[i] = (float4){0.f, 0.f, 0.f, 0.f};
}

// ---------------- counting sort ----------------
__global__ void k_hist(const int* __restrict__ dst, int* __restrict__ deg, int nE) {
  int e = blockIdx.x * blockDim.x + threadIdx.x;
  if (e < nE) atomicAdd(&deg[dst[e]], 1);
}

__global__ void k_scanA(const int* __restrict__ deg, int* __restrict__ bsum) {
  __shared__ int ss[256];
  int t = threadIdx.x;
  ss[t] = deg[blockIdx.x * 256 + t];
  __syncthreads();
  for (int off = 128; off; off >>= 1) {
    if (t < off) ss[t] += ss[t + off];
    __syncthreads();
  }
  if (t == 0) bsum[blockIdx.x] = ss[0];
}

__global__ void k_scanB(const int* __restrict__ bsum, int* __restrict__ bsumx, int NB) {
  __shared__ int sd[512];
  int t = threadIdx.x;
  int v = (t < NB) ? bsum[t] : 0;
  sd[t] = v;
  __syncthreads();
  for (int off = 1; off < 512; off <<= 1) {
    int a = (t >= off) ? sd[t - off] : 0;
    __syncthreads();
    sd[t] += a;
    __syncthreads();
  }
  if (t < NB) bsumx[t] = sd[t] - v;
}

// exclusive scan to BOTH cursor (mutated by scatter) and rowptr (kept)
__global__ void k_scanC(const int* __restrict__ deg, const int* __restrict__ bsumx,
                        int* __restrict__ cursor, int* __restrict__ rowptr) {
  __shared__ int ss[256];
  int t = threadIdx.x, i = blockIdx.x * 256 + t;
  int v = deg[i];
  ss[t] = v;
  __syncthreads();
  for (int off = 1; off < 256; off <<= 1) {
    int a = (t >= off) ? ss[t - off] : 0;
    __syncthreads();
    ss[t] += a;
    __syncthreads();
  }
  int ex = ss[t] - v + bsumx[blockIdx.x];
  cursor[i] = ex;
  rowptr[i] = ex;
}

// permute: only src and edge id (8 B random writes; ea gathered later from L3)
__global__ void k_scatter(const int* __restrict__ src, const int* __restrict__ dst,
                          int* __restrict__ cursor,
                          int* __restrict__ src_s, int* __restrict__ esort, int nE) {
  int e = blockIdx.x * blockDim.x + threadIdx.x;
  if (e >= nE) return;
  int d = dst[e];
  int pos = atomicAdd(&cursor[d], 1);
  src_s[pos] = src[e];
  esort[pos] = e;
}

// ---------------- transpose weights to bf16 ----------------
__global__ void k_prep_w(const float* __restrict__ ew2, const float* __restrict__ cw1,
                         const float* __restrict__ cw2, unsigned short* __restrict__ wT) {
  int idx = blockIdx.x * blockDim.x + threadIdx.x;
  if (idx >= 7 * 16384) return;
  int m = idx >> 14, i = idx & 16383;
  int n = i >> 7, k = i & 127;
  const float* s = (m == 0) ? ew2 : (m <= 3 ? cw1 + (size_t)(m - 1) * 16384
                                            : cw2 + (size_t)(m - 4) * 16384);
  wT[idx] = f2bf(s[k * 128 + n]);
}

// ---------------- node encoder ----------------
__global__ void k_node_enc(const float* __restrict__ x, const float* __restrict__ w,
                           const float* __restrict__ b, unsigned short* __restrict__ h16, int nN) {
  int idx = blockIdx.x * blockDim.x + threadIdx.x;
  if (idx >= nN * HID) return;
  int i = idx >> 7, j = idx & 127;
  float acc = b[j];
  const float* xr = x + (size_t)i * 7;
#pragma unroll
  for (int k = 0; k < 7; ++k) acc += xr[k] * w[k * HID + j];
  h16[idx] = f2bf(acc);
}

// ---------------- one-time edge encoder GEMM -> e8 (fp8, sorted order) ----------------
// gathers ea rows through esort (ea is L3-resident)
__global__ void __launch_bounds__(256) k_edge_gemm(
    const float* __restrict__ ea, const int* __restrict__ esort,
    const float* __restrict__ ew1, const float* __restrict__ eb1,
    const unsigned short* __restrict__ w2t, const float* __restrict__ eb2,
    unsigned char* __restrict__ e8, int nE) {
  __shared__ __attribute__((aligned(16))) unsigned short ts1[128 * LDP];
  __shared__ float eaL[384];
  __shared__ int esL[128];
  int tid = threadIdx.x;
  int e0 = blockIdx.x * 128;                      // nE % 128 == 0
  if (tid < 128) esL[tid] = esort[e0 + tid];
  __syncthreads();
  for (int i = tid; i < 384; i += 256) {
    int r = i / 3, c = i - r * 3;
    eaL[i] = ea[(size_t)esL[r] * 3 + c];
  }
  __syncthreads();
  {
    int j = tid & 127, r0 = (tid >> 7) * 64;
    float wa = ew1[j], wb = ew1[HID + j], wc = ew1[2 * HID + j], bj = eb1[j];
    for (int r = r0; r < r0 + 64; ++r) {
      float a = bj + eaL[r * 3] * wa + eaL[r * 3 + 1] * wb + eaL[r * 3 + 2] * wc;
      ts1[r * LDP + j] = f2bf(fmaxf(a, 0.f));
    }
  }
  __syncthreads();
  int wave = tid >> 6, lane = tid & 63;
  int l15 = lane & 15, quad = lane >> 4;
  int rbase = (wave >> 1) * 64, nbase = (wave & 1) * 64;
  f32x4 acc[4][4];
#pragma unroll
  for (int i = 0; i < 4; ++i)
#pragma unroll
    for (int j = 0; j < 4; ++j) acc[i][j] = (f32x4){0.f, 0.f, 0.f, 0.f};
  for (int kc = 0; kc < 4; ++kc) {
    int k0 = kc * 32 + quad * 8;
    s16x8 af[4], bf[4];
#pragma unroll
    for (int t = 0; t < 4; ++t)
      af[t] = *(const s16x8*)&ts1[(rbase + t * 16 + l15) * LDP + k0];
#pragma unroll
    for (int t = 0; t < 4; ++t)
      bf[t] = *(const s16x8*)&w2t[(size_t)(nbase + t * 16 + l15) * HID + k0];
#pragma unroll
    for (int i = 0; i < 4; ++i)
#pragma unroll
      for (int j = 0; j < 4; ++j)
        acc[i][j] = __builtin_amdgcn_mfma_f32_16x16x32_bf16(af[i], bf[j], acc[i][j], 0, 0, 0);
  }
  float ebv[4];
#pragma unroll
  for (int t = 0; t < 4; ++t) ebv[t] = eb2[nbase + t * 16 + l15];
#pragma unroll
  for (int tr = 0; tr < 4; ++tr)
#pragma unroll
    for (int reg = 0; reg < 4; ++reg) {
      int row = rbase + tr * 16 + quad * 4 + reg;   // C/D: col=lane&15, row=quad*4+reg
#pragma unroll
      for (int tc = 0; tc < 4; ++tc) {
        int col = nbase + tc * 16 + l15;
        e8[(size_t)(e0 + row) * HID + col] = f2fp8(acc[tr][tc][reg] + ebv[tc]);
      }
    }
}

// ---------------- fused CSR-aggregate + conv MLP, 32-node tile ----------------
// phase A (16B/lane, fp8 e): node-aligned groups of 4 edges; quad q owns edge
//   gb+q; lane covers 8 cols: e via uint2 (8 B fp8), h via uint4 (16 B bf16).
//   fp32 per-quad partials; node-end: shfl_xor butterfly + quad-0 b128 RMW.
__global__ void __launch_bounds__(256) k_conv_csr(
    const unsigned short* __restrict__ h16in, const unsigned char* __restrict__ e8,
    const int* __restrict__ src_s, const int* __restrict__ rowptr,
    const unsigned short* __restrict__ w1t, const float* __restrict__ b1,
    const unsigned short* __restrict__ w2t, const float* __restrict__ b2,
    unsigned short* __restrict__ h16out, int nN) {
  __shared__ __attribute__((aligned(16))) unsigned short zs[32 * LDP];
  __shared__ int rpS[4][12];
  int tid = threadIdx.x;
  int n0 = blockIdx.x * 32;
  int wave = tid >> 6, lane = tid & 63;
  int l15 = lane & 15, quad = lane >> 4;
  // phase A
  {
    int c16 = l15 * 8;                  // col base (8 cols per lane)
    int c2 = lane * 2;
    int wbase = wave * 8;
    int nodeBase = n0 + wbase;
    int nCnt = nN - nodeBase; if (nCnt > 8) nCnt = 8; if (nCnt < 0) nCnt = 0;
#pragma unroll
    for (int i = 0; i < 8; ++i) {
      int n = nodeBase + i;
      unsigned int hv = 0u;
      if (n < nN) hv = *(const unsigned int*)&h16in[(size_t)n * HID + c2];
      *(unsigned int*)&zs[(wbase + i) * LDP + c2] = hv;
    }
    if (lane < 9) {
      int i = (lane < nCnt) ? lane : nCnt;
      rpS[wave][lane] = (nCnt > 0) ? rowptr[nodeBase + i] : 0;
    }
    if (nCnt > 0) {
      int gb = rpS[wave][0];
      int gEnd = rpS[wave][8];
      int ni = 0;
      while (ni < 8 && rpS[wave][ni + 1] <= gb) ++ni;
      int re = (ni < 8) ? rpS[wave][ni + 1] : gb;
      float acc[8];
#pragma unroll
      for (int j = 0; j < 8; ++j) acc[j] = 0.f;

      int eixA = 0, eixB = 0, eixC = 0, svA = 0, svB = 0, svC = 0;
      int niA = 0, niB = 0, niC = 0;
      bool vA = false, vB = false, vC = false, lA = false, lB = false, lC = false;
      uint2 evA, evB;
      uint4 hvA, hvB;
      bool aA = false, aB = false, aC = false;

#define PS(eix, sv, v, l, nis)                                   \
  { int gq = gb + quad;                                          \
    eix = (gq < re) ? gq : (re - 1);                             \
    v = (gq < re);                                               \
    l = (gb + 4 >= re);                                          \
    nis = ni;                                                    \
    sv = src_s[eix];                                             \
    gb = (gb + 4 < re) ? (gb + 4) : re;                          \
    if (gb >= re) {                                              \
      while (ni < 8 && rpS[wave][ni + 1] <= gb) ++ni;            \
      if (ni < 8) re = rpS[wave][ni + 1];                        \
    } }
#define PEH(ev, hv, eix, sv)                                     \
  { ev = *(const uint2*)&e8[(size_t)eix * HID + c16];            \
    hv = *(const uint4*)&h16in[(size_t)sv * HID + c16]; }
#define FOLDX(ev, hv, v, l, nis)                                 \
  { const unsigned int* ew = (const unsigned int*)&ev;           \
    const unsigned int* hw = (const unsigned int*)&hv;           \
    if (v) {                                                     \
      _Pragma("unroll")                                          \
      for (int j = 0; j < 2; ++j) {                              \
        f32x2 pa = __builtin_amdgcn_cvt_pk_f32_fp8(ew[j], false); \
        f32x2 pb = __builtin_amdgcn_cvt_pk_f32_fp8(ew[j], true);  \
        acc[4*j+0] += fmaxf(asf(hw[2*j] << 16) + pa[0], 0.f);    \
        acc[4*j+1] += fmaxf(asf(hw[2*j] & 0xffff0000u) + pa[1], 0.f); \
        acc[4*j+2] += fmaxf(asf(hw[2*j+1] << 16) + pb[0], 0.f);  \
        acc[4*j+3] += fmaxf(asf(hw[2*j+1] & 0xffff0000u) + pb[1], 0.f); \
      }                                                          \
    }                                                            \
    if (l) {                                                     \
      _Pragma("unroll")                                          \
      for (int j = 0; j < 8; ++j) {                              \
        acc[j] += __shfl_xor(acc[j], 16);                        \
        acc[j] += __shfl_xor(acc[j], 32);                        \
      }                                                          \
      if (quad == 0) {                                           \
        int row = wbase + nis;                                   \
        uint4 z = *(const uint4*)&zs[row * LDP + c16];           \
        unsigned int* zw = (unsigned int*)&z;                    \
        _Pragma("unroll")                                        \
        for (int j = 0; j < 4; ++j) {                            \
          float z0 = asf(zw[j] << 16) + acc[2*j];                \
          float z1 = asf(zw[j] & 0xffff0000u) + acc[2*j+1];      \
          zw[j] = (unsigned int)f2bf(z0) | ((unsigned int)f2bf(z1) << 16); \
        }                                                        \
        *(uint4*)&zs[row * LDP + c16] = z;                       \
      }                                                          \
      _Pragma("unroll")                                          \
      for (int j = 0; j < 8; ++j) acc[j] = 0.f;                  \
    } }

      if (gb < gEnd) { PS(eixA, svA, vA, lA, niA) aA = true; }
      if (gb < gEnd) { PS(eixB, svB, vB, lB, niB) aB = true; }
      if (aA) PEH(evA, hvA, eixA, svA)
      while (aA) {
        aC = (gb < gEnd);
        if (aC) PS(eixC, svC, vC, lC, niC)
        if (aB) PEH(evB, hvB, eixB, svB)
        FOLDX(evA, hvA, vA, lA, niA)
        aA = aB; evA = evB; hvA = hvB; vA = vB; lA = lB; niA = niB; eixA = eixB; svA = svB;
        aB = aC; eixB = eixC; svB = svC; vB = vC; lB = lC; niB = niC;
      }
#undef PS
#undef PEH
#undef FOLDX
    }
  }
  __syncthreads();
  int rbase = (wave >> 1) * 16, nbase = (wave & 1) * 64;
  f32x4 acc[4];
#pragma unroll
  for (int j = 0; j < 4; ++j) acc[j] = (f32x4){0.f, 0.f, 0.f, 0.f};
  for (int kc = 0; kc < 4; ++kc) {
    int k0 = kc * 32 + quad * 8;
    s16x8 af, bf[4];
    af = *(const s16x8*)&zs[(rbase + l15) * LDP + k0];
#pragma unroll
    for (int t = 0; t < 4; ++t)
      bf[t] = *(const s16x8*)&w1t[(size_t)(nbase + t * 16 + l15) * HID + k0];
#pragma unroll
    for (int j = 0; j < 4; ++j)
      acc[j] = __builtin_amdgcn_mfma_f32_16x16x32_bf16(af, bf[j], acc[j], 0, 0, 0);
  }
  __syncthreads();
  {
    float bv[4];
#pragma unroll
    for (int t = 0; t < 4; ++t) bv[t] = b1[nbase + t * 16 + l15];
#pragma unroll
    for (int tc = 0; tc < 4; ++tc)
#pragma unroll
      for (int reg = 0; reg < 4; ++reg) {
        int row = rbase + quad * 4 + reg;
        int col = nbase + tc * 16 + l15;
        zs[row * LDP + col] = f2bf(fmaxf(acc[tc][reg] + bv[tc], 0.f));
      }
  }
  __syncthreads();
#pragma unroll
  for (int j = 0; j < 4; ++j) acc[j] = (f32x4){0.f, 0.f, 0.f, 0.f};
  for (int kc = 0; kc < 4; ++kc) {
    int k0 = kc * 32 + quad * 8;
    s16x8 af, bf[4];
    af = *(const s16x8*)&zs[(rbase + l15) * LDP + k0];
#pragma unroll
    for (int t = 0; t < 4; ++t)
      bf[t] = *(const s16x8*)&w2t[(size_t)(nbase + t * 16 + l15) * HID + k0];
#pragma unroll
    for (int j = 0; j < 4; ++j)
      acc[j] = __builtin_amdgcn_mfma_f32_16x16x32_bf16(af, bf[j], acc[j], 0, 0, 0);
  }
  {
    float bv[4];
#pragma unroll
    for (int t = 0; t < 4; ++t) bv[t] = b2[nbase + t * 16 + l15];
#pragma unroll
    for (int reg = 0; reg < 4; ++reg) {
      int grow = n0 + rbase + quad * 4 + reg;
      if (grow < nN) {
#pragma unroll
        for (int tc = 0; tc < 4; ++tc) {
          int col = nbase + tc * 16 + l15;
          h16out[(size_t)grow * HID + col] = f2bf(fmaxf(acc[tc][reg] + bv[tc], 0.f));
        }
      }
    }
  }
}

// ---------------- counts ----------------
__global__ void k_counts(const int* __restrict__ batch, int* __restrict__ cnts, int nN) {
  int i = blockIdx.x * blockDim.x + threadIdx.x;
  if (i < nN) atomicAdd(&cnts[batch[i]], 1);
}

// ---------------- segment-reduced pool (batch sorted) ----------------
__global__ void __launch_bounds__(256) k_pool2(
    const unsigned short* __restrict__ h16, const int* __restrict__ batch,
    float* __restrict__ g, int nN) {
  __shared__ int bL[128];
  int tid = threadIdx.x;
  int n0 = blockIdx.x * 128;
  if (tid < 128) {
    int n = n0 + tid;
    bL[tid] = (n < nN) ? batch[n] : -1;
  }
  __syncthreads();
  int half = tid >> 7, col = tid & 127;
  int rs = half * 64;
  int cur = -1;
  float s = 0.f;
  for (int r = rs; r < rs + 64; ++r) {
    int b = bL[r];
    float v = (b >= 0) ? bf2f((unsigned int)h16[(size_t)(n0 + r) * HID + col]) : 0.f;
    if (b != cur) {
      if (cur >= 0) atomicAdd(&g[(size_t)cur * HID + col], s);
      cur = b; s = v;
    } else s += v;
  }
  if (cur >= 0) atomicAdd(&g[(size_t)cur * HID + col], s);
}

// ---------------- heads ----------------
__global__ void __launch_bounds__(128) k_head(
    const float* __restrict__ g, const int* __restrict__ counts,
    const float* __restrict__ clw1, const float* __restrict__ clb1,
    const float* __restrict__ clw2, const float* __restrict__ clb2,
    const float* __restrict__ rw1, const float* __restrict__ rb1,
    const float* __restrict__ rw2, const float* __restrict__ rb2,
    float* __restrict__ out, int nG) {
  __shared__ float gs[HID];
  int b = blockIdx.x;
  int tid = threadIdx.x;
  float cnt = fmaxf((float)counts[b], 1.f);
  gs[tid] = g[b * HID + tid] / cnt;
  __syncthreads();
  int wave = tid >> 6, lane = tid & 63;
  const float* w1 = wave ? rw1 : clw1;
  const float* b1 = wave ? rb1 : clb1;
  const float* w2 = wave ? rw2 : clw2;
  const float* b2 = wave ? rb2 : clb2;
  float acc = b1[lane];
  for (int k = 0; k < HID; ++k) acc += gs[k] * w1[k * 64 + lane];
  acc = fmaxf(acc, 0.f) * w2[lane];
#pragma unroll
  for (int off = 32; off; off >>= 1) acc += __shfl_down(acc, off);
  if (lane == 0) out[wave * nG + b] = acc + b2[0];
}

extern "C" void kernel_launch(void* const* d_in, const int* in_sizes, int n_in,
                              void* d_out, int out_size, void* d_ws, size_t ws_size,
                              hipStream_t stream) {
  const float* x      = (const float*)d_in[0];
  const float* ea     = (const float*)d_in[1];
  const int*   eidx   = (const int*)d_in[2];
  const int*   batch  = (const int*)d_in[3];
  const float* node_w = (const float*)d_in[4];
  const float* node_b = (const float*)d_in[5];
  const float* ew1    = (const float*)d_in[6];
  const float* eb1    = (const float*)d_in[7];
  const float* ew2    = (const float*)d_in[8];
  const float* eb2    = (const float*)d_in[9];
  const float* cw1    = (const float*)d_in[10];
  const float* cb1    = (const float*)d_in[11];
  const float* cw2    = (const float*)d_in[12];
  const float* cb2    = (const float*)d_in[13];
  const float* clw1   = (const float*)d_in[14];
  const float* clb1   = (const float*)d_in[15];
  const float* clw2   = (const float*)d_in[16];
  const float* clb2   = (const float*)d_in[17];
  const float* rw1    = (const float*)d_in[18];
  const float* rb1    = (const float*)d_in[19];
  const float* rw2    = (const float*)d_in[20];
  const float* rb2    = (const float*)d_in[21];
  float* out = (float*)d_out;

  int nN = in_sizes[3];        // 100000
  int nE = in_sizes[2] / 2;    // 640000 (divisible by 128)
  int nG = out_size / 2;       // 2048
  const int* src = eidx;
  const int* dst = eidx + nE;

  int NB = (nN + 255) / 256;
  int bins = NB * 256;

  // ---- workspace (~140 MB) ----
  size_t hN = (size_t)nN * HID;
  size_t gN = (size_t)nG * HID;
  float* g    = (float*)d_ws;                       // gN
  int*   cnts = (int*)(g + gN);                     // nG
  unsigned short* wT   = (unsigned short*)(cnts + nG);  // 7*16384
  unsigned short* h16a = wT + 7 * 16384;            // hN
  unsigned short* h16b = h16a + hN;                 // hN
  int* deg    = (int*)(h16b + hN);                  // bins
  int* cursor = deg + bins;                         // bins
  int* rowptr = cursor + bins;                      // bins
  int* bsum   = rowptr + bins;                      // 512
  int* bsumx  = bsum + 512;                         // 512
  int* src_s  = bsumx + 512;                        // nE
  int* esort  = src_s + nE;                         // nE
  unsigned char* e8 = (unsigned char*)(esort + nE); // nE*128 fp8

  // ---- counting sort of edges by dst (builds CSR rowptr + permutation) ----
  k_zero4<<<(int)((bins / 4 + 255) / 256), 256, 0, stream>>>((float4*)deg, bins / 4);
  k_hist<<<(nE + 255) / 256, 256, 0, stream>>>(dst, deg, nE);
  k_scanA<<<NB, 256, 0, stream>>>(deg, bsum);
  k_scanB<<<1, 512, 0, stream>>>(bsum, bsumx, NB);
  k_scanC<<<NB, 256, 0, stream>>>(deg, bsumx, cursor, rowptr);
  k_scatter<<<(nE + 255) / 256, 256, 0, stream>>>(src, dst, cursor, src_s, esort, nE);

  k_prep_w<<<(7 * 16384 + 255) / 256, 256, 0, stream>>>(ew2, cw1, cw2, wT);
  k_edge_gemm<<<nE / 128, 256, 0, stream>>>(ea, esort, ew1, eb1, wT, eb2, e8, nE);
  k_node_enc<<<(nN * HID + 255) / 256, 256, 0, stream>>>(x, node_w, node_b, h16a, nN);

  // ping-pong: A->B, B->A, A->B  (final in h16b)
  unsigned short* hin  = h16a;
  unsigned short* hout = h16b;
  for (int l = 0; l < 3; ++l) {
    k_conv_csr<<<(nN + 31) / 32, 256, 0, stream>>>(
        hin, e8, src_s, rowptr,
        wT + (size_t)(1 + l) * 16384, cb1 + (size_t)l * HID,
        wT + (size_t)(4 + l) * 16384, cb2 + (size_t)l * HID, hout, nN);
    unsigned short* t = hin; hin = hout; hout = t;
  }

  k_zero4<<<(int)(((gN + nG) / 4 + 255) / 256), 256, 0, stream>>>((float4*)g, (gN + nG) / 4);
  k_counts<<<(nN + 255) / 256, 256, 0, stream>>>(batch, cnts, nN);
  k_pool2<<<(nN + 127) / 128, 256, 0, stream>>>(hin, batch, g, nN);
  k_head<<<nG, 128, 0, stream>>>(g, cnts, clw1, clb1, clw2, clb2,
                                 rw1, rb1, rw2, rb2, out, nG);
}